// Round 26
// baseline (487.414 us; speedup 1.0000x reference)
//
#include <hip/hip_runtime.h>
#include <hip/hip_fp16.h>
#include <cmath>

#define DEVI static __device__ __forceinline__

constexpr int HIDn = 128, OUTn = 64;
constexpr int NCn = 50000, NDn = 50000, En = 400000;
constexpr int SCAN_N = 150000, SCAN_BLK = 1024;
constexpr int SCAN_NB = (SCAN_N + SCAN_BLK - 1) / SCAN_BLK;   // 147

typedef __attribute__((ext_vector_type(8))) short bf16x8;
typedef __attribute__((ext_vector_type(4))) float f32x4;

// monotonic float->uint mapping for atomicMax on floats (handles signs)
DEVI unsigned fmap(float f) {
  int i = __float_as_int(f);
  return (i < 0) ? ~((unsigned)i) : (((unsigned)i) | 0x80000000u);
}
DEVI float fdecode(unsigned u) {
  int i = (u & 0x80000000u) ? (int)(u & 0x7fffffffu) : (int)(~u);
  return __int_as_float(i);
}

DEVI float tanh_fast(float x) {           // 1 - 2/(e^{2x}+1); saturates correctly
  float e = __expf(2.f * x);
  return 1.f - __fdividef(2.f, e + 1.f);
}

DEVI unsigned short f2bf(float x) {       // fp32 -> bf16 RNE
  unsigned u = __float_as_uint(x);
  return (unsigned short)((u + 0x7FFFu + ((u >> 16) & 1u)) >> 16);
}
DEVI float bf2f(unsigned short h) {
  unsigned u = ((unsigned)h) << 16;
  return __uint_as_float(u);
}

// ---- vectorized 8-wide A-row load + fused transform (value-based) -------
// MODE: 0=plain, 1=elu(x), 2=elu(w2*a+w3*b). HALF: input dtype fp16.
template<int MODE, int HALF>
DEVI void loadrow8(float* __restrict__ tmp,
                   const void* __restrict__ A, const void* __restrict__ A2,
                   float w2, float w3, size_t base)
{
  float v[8];
  if (HALF) {
    float4 raw = *(const float4*)((const __half*)A + base);
    const __half2* h2 = (const __half2*)&raw;
    #pragma unroll
    for (int j = 0; j < 4; ++j) {
      float2 f = __half22float2(h2[j]);
      v[2 * j] = f.x; v[2 * j + 1] = f.y;
    }
  } else {
    const float4* p = (const float4*)((const float*)A + base);
    float4 u0 = p[0], u1 = p[1];
    v[0] = u0.x; v[1] = u0.y; v[2] = u0.z; v[3] = u0.w;
    v[4] = u1.x; v[5] = u1.y; v[6] = u1.z; v[7] = u1.w;
  }
  if (MODE == 2) {
    float vb[8];
    if (HALF) {
      float4 raw = *(const float4*)((const __half*)A2 + base);
      const __half2* h2 = (const __half2*)&raw;
      #pragma unroll
      for (int j = 0; j < 4; ++j) {
        float2 f = __half22float2(h2[j]);
        vb[2 * j] = f.x; vb[2 * j + 1] = f.y;
      }
    } else {
      const float4* q = (const float4*)((const float*)A2 + base);
      float4 t0 = q[0], t1 = q[1];
      vb[0] = t0.x; vb[1] = t0.y; vb[2] = t0.z; vb[3] = t0.w;
      vb[4] = t1.x; vb[5] = t1.y; vb[6] = t1.z; vb[7] = t1.w;
    }
    #pragma unroll
    for (int i = 0; i < 8; ++i) v[i] = w2 * v[i] + w3 * vb[i];
  }
  if (MODE >= 1) {
    #pragma unroll
    for (int i = 0; i < 8; ++i) v[i] = (v[i] > 0.f) ? v[i] : (__expf(v[i]) - 1.f);
  }
  #pragma unroll
  for (int i = 0; i < 8; ++i) tmp[i] = v[i];
}

template<int MODE, int HALF>
DEVI bf16x8 packrow8(const void* __restrict__ A, const void* __restrict__ A2,
                     float w2, float w3, size_t base)
{
  float t[8];
  loadrow8<MODE, HALF>(t, A, A2, w2, w3, base);
  bf16x8 r;
  #pragma unroll
  for (int i = 0; i < 8; ++i) r[i] = (short)f2bf(t[i]);
  return r;
}

// ====== merged MFMA GEMM (c & d paths) + fused attention dots ============
// BM=128 tile: each wave owns 2 row-tiles (32 rows). B (fragment order)
// staged once per chunk in LDS and amortized over 2x rows; single-depth
// register prefetch issued before the barrier (round-23 schedule).
template<int KI, int MODEc, int MODEd, int IN16, int OUT16>
__global__ __launch_bounds__(256)
void gemm2_mfma(const void* __restrict__ Ac, const void* __restrict__ Ac2,
                const float* __restrict__ wv,
                const unsigned short* __restrict__ WcH, const unsigned short* __restrict__ WcL,
                const float* __restrict__ bc, void* __restrict__ Cc,
                const void* __restrict__ Ad,
                const unsigned short* __restrict__ WdH, const unsigned short* __restrict__ WdL,
                const float* __restrict__ bd, void* __restrict__ Cd,
                int N,
                const float* __restrict__ avc0, const float* __restrict__ avc1,
                const float* __restrict__ avc2, const float* __restrict__ avc3,
                const float* __restrict__ avd0, const float* __restrict__ avd1,
                float* __restrict__ doc0, float* __restrict__ doc1,
                float* __restrict__ doc2, float* __restrict__ doc3,
                float* __restrict__ dod0, float* __restrict__ dod1)
{
  __shared__ float As[128][44];                // 22.5 KB, stride 44 -> 2-way banks
  __shared__ unsigned short BhS[4096];         // 8 KB (one chunk, fragment order)
  __shared__ unsigned short BlS[4096];         // 8 KB
  constexpr int NC = KI / 32;
  const bool isC = (blockIdx.y == 0);
  const void* A  = isC ? Ac : Ad;
  const void* A2 = isC ? Ac2 : nullptr;
  const unsigned short* WH = isC ? WcH : WdH;
  const unsigned short* WL = isC ? WcL : WdL;
  const float* bias = isC ? bc : bd;
  void* Cv = isC ? Cc : Cd;
  float w2 = 0.f, w3 = 0.f;
  if (MODEc == 2) { if (isC) { w2 = wv[2]; w3 = wv[3]; } }

  const int tid = threadIdx.x;
  const int w = tid >> 6, lane = tid & 63;
  const int m = lane & 15, b4 = lane >> 4;
  const int row0 = blockIdx.x * 128;
  const int row0w = row0 + w * 32;             // wave base: 32 rows (2 row-tiles)

  // staging thread roles: two 8-col slots per thread (rows rA0, rA0+64)
  const int rA0 = tid >> 2, kqA = (tid & 3) << 3;
  const int rA1 = rA0 + 64;
  const int rowA0 = row0 + rA0;
  const int rowA1 = row0 + rA1;

  f32x4 acc[2][8];
  #pragma unroll
  for (int rt = 0; rt < 2; ++rt)
    #pragma unroll
    for (int t = 0; t < 8; ++t) acc[rt][t] = (f32x4){0.f, 0.f, 0.f, 0.f};

  float tA[16];                                 // two staged rows (8+8)
  float4 rbh0, rbh1, rbl0, rbl1;

  auto loadA = [&](int k0) {
    if (rowA0 < N) {
      if (isC) loadrow8<MODEc, IN16>(tA, A, A2, w2, w3, (size_t)rowA0 * KI + k0 + kqA);
      else     loadrow8<MODEd, IN16>(tA, A, nullptr, 0.f, 0.f, (size_t)rowA0 * KI + k0 + kqA);
    } else {
      #pragma unroll
      for (int i = 0; i < 8; ++i) tA[i] = 0.f;
    }
    if (rowA1 < N) {
      if (isC) loadrow8<MODEc, IN16>(tA + 8, A, A2, w2, w3, (size_t)rowA1 * KI + k0 + kqA);
      else     loadrow8<MODEd, IN16>(tA + 8, A, nullptr, 0.f, 0.f, (size_t)rowA1 * KI + k0 + kqA);
    } else {
      #pragma unroll
      for (int i = 0; i < 8; ++i) tA[8 + i] = 0.f;
    }
  };
  auto loadB = [&](int c) {
    const float4* ph = (const float4*)(WH + (size_t)c * 4096 + tid * 16);
    const float4* pl = (const float4*)(WL + (size_t)c * 4096 + tid * 16);
    rbh0 = ph[0]; rbh1 = ph[1];
    rbl0 = pl[0]; rbl1 = pl[1];
  };

  loadA(0);
  loadB(0);

  for (int c = 0; c < NC; ++c) {
    // write staged regs to LDS (all linear/coalesced)
    *(float4*)&As[rA0][kqA]     = make_float4(tA[0], tA[1], tA[2], tA[3]);
    *(float4*)&As[rA0][kqA + 4] = make_float4(tA[4], tA[5], tA[6], tA[7]);
    *(float4*)&As[rA1][kqA]     = make_float4(tA[8], tA[9], tA[10], tA[11]);
    *(float4*)&As[rA1][kqA + 4] = make_float4(tA[12], tA[13], tA[14], tA[15]);
    *(float4*)&BhS[tid * 16]     = rbh0;
    *(float4*)&BhS[tid * 16 + 8] = rbh1;
    *(float4*)&BlS[tid * 16]     = rbl0;
    *(float4*)&BlS[tid * 16 + 8] = rbl1;

    // prefetch next chunk BEFORE the barrier (regs already consumed)
    if (c + 1 < NC) { loadA((c + 1) * 32); loadB(c + 1); }
    __syncthreads();

    bf16x8 ah0, al0, ah1, al1;
    {
      const float* ap = &As[row0w - row0 + m][b4 * 8];      // rt=0: rows w*32+m
      float4 u0 = *(const float4*)ap;
      float4 u1 = *(const float4*)(ap + 4);
      float t8[8] = {u0.x, u0.y, u0.z, u0.w, u1.x, u1.y, u1.z, u1.w};
      #pragma unroll
      for (int i = 0; i < 8; ++i) {
        unsigned short h = f2bf(t8[i]);
        ah0[i] = (short)h;
        al0[i] = (short)f2bf(t8[i] - bf2f(h));
      }
    }
    {
      const float* ap = &As[row0w - row0 + 16 + m][b4 * 8]; // rt=1: rows w*32+16+m
      float4 u0 = *(const float4*)ap;
      float4 u1 = *(const float4*)(ap + 4);
      float t8[8] = {u0.x, u0.y, u0.z, u0.w, u1.x, u1.y, u1.z, u1.w};
      #pragma unroll
      for (int i = 0; i < 8; ++i) {
        unsigned short h = f2bf(t8[i]);
        ah1[i] = (short)h;
        al1[i] = (short)f2bf(t8[i] - bf2f(h));
      }
    }
    #pragma unroll
    for (int t = 0; t < 8; ++t) {
      const int fi = (t * 64 + lane) * 8;
      bf16x8 bh = *(const bf16x8*)&BhS[fi];
      bf16x8 bl = *(const bf16x8*)&BlS[fi];
      acc[0][t] = __builtin_amdgcn_mfma_f32_16x16x32_bf16(ah0, bh, acc[0][t], 0, 0, 0);
      acc[0][t] = __builtin_amdgcn_mfma_f32_16x16x32_bf16(al0, bh, acc[0][t], 0, 0, 0);
      acc[0][t] = __builtin_amdgcn_mfma_f32_16x16x32_bf16(ah0, bl, acc[0][t], 0, 0, 0);
      acc[1][t] = __builtin_amdgcn_mfma_f32_16x16x32_bf16(ah1, bh, acc[1][t], 0, 0, 0);
      acc[1][t] = __builtin_amdgcn_mfma_f32_16x16x32_bf16(al1, bh, acc[1][t], 0, 0, 0);
      acc[1][t] = __builtin_amdgcn_mfma_f32_16x16x32_bf16(ah1, bl, acc[1][t], 0, 0, 0);
    }
    __syncthreads();
  }

  // ---- epilogue: bias + C store ----
  float bt[8];
  #pragma unroll
  for (int t = 0; t < 8; ++t) bt[t] = bias[t * 16 + m];

  #pragma unroll
  for (int rt = 0; rt < 2; ++rt) {
    #pragma unroll
    for (int t = 0; t < 8; ++t) {
      const int col = t * 16 + m;
      #pragma unroll
      for (int r = 0; r < 4; ++r) {
        const int row = row0w + rt * 16 + b4 * 4 + r;
        if (row < N) {
          float v = acc[rt][t][r] + bt[t];
          if (OUT16) ((__half*)Cv)[(size_t)row * 128 + col] = __float2half(v);
          else       ((float*)Cv)[(size_t)row * 128 + col] = v;
        }
      }
    }
  }

  // ---- fused attention dots: per (row, head) reduce over 16 m-lanes ----
  const float* avp[4];
  float* dop[4];
  int nv;
  if (isC) {
    avp[0] = avc0; avp[1] = avc1; avp[2] = avc2; avp[3] = avc3;
    dop[0] = doc0; dop[1] = doc1; dop[2] = doc2; dop[3] = doc3; nv = 4;
  } else {
    avp[0] = avd0; avp[1] = avd1; avp[2] = avd0; avp[3] = avd1;
    dop[0] = dod0; dop[1] = dod1; dop[2] = dod0; dop[3] = dod1; nv = 2;
  }
  float avv[4][8];
  #pragma unroll
  for (int v = 0; v < 4; ++v) {
    if (v < nv) {
      #pragma unroll
      for (int t = 0; t < 8; ++t) avv[v][t] = avp[v][t * 16 + m];
    }
  }
  #pragma unroll
  for (int rt = 0; rt < 2; ++rt) {
    #pragma unroll
    for (int h = 0; h < 4; ++h) {
      #pragma unroll
      for (int v = 0; v < 4; ++v) {
        if (v < nv) {
          #pragma unroll
          for (int r = 0; r < 4; ++r) {
            float p = (acc[rt][2 * h][r] + bt[2 * h]) * avv[v][2 * h]
                    + (acc[rt][2 * h + 1][r] + bt[2 * h + 1]) * avv[v][2 * h + 1];
            p += __shfl_xor(p, 1);
            p += __shfl_xor(p, 2);
            p += __shfl_xor(p, 4);
            p += __shfl_xor(p, 8);
            if (m == 0) {
              const int row = row0w + rt * 16 + b4 * 4 + r;
              if (row < N) dop[v][(size_t)row * 4 + h] = p;
            }
          }
        }
      }
    }
  }
}

// ================= CSR build: hist + 3-pass scan + fill ==================
__global__ void hist3(const int* __restrict__ ei0, const int* __restrict__ ei1,
                      const int* __restrict__ ei2, int* __restrict__ deg)
{
  int gid = blockIdx.x * blockDim.x + threadIdx.x;
  if (gid >= 3 * En) return;
  int g = gid / En, e = gid - g * En;
  const int* ei = (g == 0) ? ei0 : (g == 1) ? ei1 : ei2;
  atomicAdd(&deg[g * 50000 + ei[En + e]], 1);
}

__global__ void scan_pass1(const int* __restrict__ deg, int* __restrict__ incl,
                           int* __restrict__ bsum)
{
  __shared__ int wsum[16];
  int tid = threadIdx.x;
  int gid = blockIdx.x * SCAN_BLK + tid;
  int v = (gid < SCAN_N) ? deg[gid] : 0;
  int lane = tid & 63, w = tid >> 6;
  int x = v;
  #pragma unroll
  for (int off = 1; off < 64; off <<= 1) {
    int y = __shfl_up(x, off);
    if (lane >= off) x += y;
  }
  if (lane == 63) wsum[w] = x;
  __syncthreads();
  if (tid == 0) {
    int s = 0;
    #pragma unroll
    for (int ww = 0; ww < 16; ++ww) { int t = wsum[ww]; wsum[ww] = s; s += t; }
    bsum[blockIdx.x] = s;
  }
  __syncthreads();
  x += wsum[w];
  if (gid < SCAN_N) incl[gid] = x;
}

__global__ void scan_pass2(int* __restrict__ bsum, int nb)
{
  __shared__ int wsum[16];
  int tid = threadIdx.x;
  int v = (tid < nb) ? bsum[tid] : 0;
  int lane = tid & 63, w = tid >> 6;
  int x = v;
  #pragma unroll
  for (int off = 1; off < 64; off <<= 1) {
    int y = __shfl_up(x, off);
    if (lane >= off) x += y;
  }
  if (lane == 63) wsum[w] = x;
  __syncthreads();
  if (tid == 0) {
    int s = 0;
    #pragma unroll
    for (int ww = 0; ww < 16; ++ww) { int t = wsum[ww]; wsum[ww] = s; s += t; }
  }
  __syncthreads();
  x += wsum[w];
  if (tid < nb) bsum[tid] = x - v;
}

__global__ void scan_pass3(const int* __restrict__ incl, const int* __restrict__ bsum,
                           int* __restrict__ offs)
{
  int gid = blockIdx.x * SCAN_BLK + threadIdx.x;
  if (gid == 0) offs[0] = 0;
  if (gid < SCAN_N) offs[gid + 1] = incl[gid] + bsum[gid / SCAN_BLK];
}

__global__ void fill3(const int* __restrict__ ei0, const int* __restrict__ ei1,
                      const int* __restrict__ ei2, const int* __restrict__ offs,
                      int* __restrict__ cursor, int* __restrict__ elist)
{
  int gid = blockIdx.x * blockDim.x + threadIdx.x;
  if (gid >= 3 * En) return;
  int g = gid / En, e = gid - g * En;
  const int* ei = (g == 0) ? ei0 : (g == 1) ? ei1 : ei2;
  int s = ei[e], d = g * 50000 + ei[En + e];
  int p = atomicAdd(&cursor[d], 1);
  elist[offs[d] + p] = s;
}

// ---- weight prep: all B operands in MFMA fragment order -----------------
__global__ void wprep(const float* __restrict__ k1W, const float* __restrict__ k2W,
                      const float* __restrict__ pW,
                      const float* __restrict__ W1c, const float* __restrict__ W1d,
                      const float* __restrict__ W2c, const float* __restrict__ W2d,
                      unsigned short* kW1t, unsigned short* kW2t, unsigned short* pWt,
                      unsigned short* W1cH, unsigned short* W1cL,
                      unsigned short* W1dH, unsigned short* W1dL,
                      unsigned short* W2cH, unsigned short* W2cL,
                      unsigned short* W2dH, unsigned short* W2dL)
{
  int gid = blockIdx.x * 256 + threadIdx.x;
  if (gid < 16384) {                       // k1W: 128x128
    int i = gid, k = i >> 7, col = i & 127;
    int ks = k >> 5, b4 = (k >> 3) & 3, j = k & 7, t = col >> 4, m = col & 15;
    kW1t[(size_t)(((t * 4 + ks) * 64) + m + 16 * b4) * 8 + j] = f2bf(k1W[i]);
  } else if (gid < 32768) {                // k2W: 128x128
    int i = gid - 16384, k = i >> 7, col = i & 127;
    int ks = k >> 5, b4 = (k >> 3) & 3, j = k & 7, t = col >> 4, m = col & 15;
    kW2t[(size_t)(((t * 4 + ks) * 64) + m + 16 * b4) * 8 + j] = f2bf(k2W[i]);
  } else if (gid < 40960) {                // pW: 128x64
    int i = gid - 32768, k = i / 64, col = i - k * 64;
    int ks = k >> 5, b4 = (k >> 3) & 3, j = k & 7, t = col >> 4, m = col & 15;
    pWt[(size_t)(((t * 4 + ks) * 64) + m + 16 * b4) * 8 + j] = f2bf(pW[i]);
  } else if (gid < 73728) {                // W1c: 256x128
    int i = gid - 40960, k = i >> 7, col = i & 127;
    int c = k >> 5, b4 = (k >> 3) & 3, j = k & 7, t = col >> 4, m = col & 15;
    size_t f = (size_t)(((c * 8 + t) * 64) + m + 16 * b4) * 8 + j;
    float v = W1c[i]; unsigned short h = f2bf(v);
    W1cH[f] = h; W1cL[f] = f2bf(v - bf2f(h));
  } else if (gid < 106496) {               // W1d: 256x128
    int i = gid - 73728, k = i >> 7, col = i & 127;
    int c = k >> 5, b4 = (k >> 3) & 3, j = k & 7, t = col >> 4, m = col & 15;
    size_t f = (size_t)(((c * 8 + t) * 64) + m + 16 * b4) * 8 + j;
    float v = W1d[i]; unsigned short h = f2bf(v);
    W1dH[f] = h; W1dL[f] = f2bf(v - bf2f(h));
  } else if (gid < 122880) {               // W2c: 128x128
    int i = gid - 106496, k = i >> 7, col = i & 127;
    int c = k >> 5, b4 = (k >> 3) & 3, j = k & 7, t = col >> 4, m = col & 15;
    size_t f = (size_t)(((c * 8 + t) * 64) + m + 16 * b4) * 8 + j;
    float v = W2c[i]; unsigned short h = f2bf(v);
    W2cH[f] = h; W2cL[f] = f2bf(v - bf2f(h));
  } else if (gid < 139264) {               // W2d: 128x128
    int i = gid - 122880, k = i >> 7, col = i & 127;
    int c = k >> 5, b4 = (k >> 3) & 3, j = k & 7, t = col >> 4, m = col & 15;
    size_t f = (size_t)(((c * 8 + t) * 64) + m + 16 * b4) * 8 + j;
    float v = W2d[i]; unsigned short h = f2bf(v);
    W2dH[f] = h; W2dL[f] = f2bf(v - bf2f(h));
  }
}

// ==== FUSED edge attention (CSR, fp16 h, lane-specialized softmax) =======
struct EdgeOp {
  const int* offs; const int* elist;
  const float* sdot; const float* ddot;
  const __half* hsrc; __half* out;
};

DEVI void csr_att_body(const EdgeOp& op, int dst, int lane)
{
  const int i0 = op.offs[dst], i1 = op.offs[dst + 1];
  const int hB = lane >> 4;
  const float ddv = op.ddot[dst * 4 + hB];
  const __half* hsrc = op.hsrc;
  const float* sdot = op.sdot;
  const int* el = op.elist;
  const int wsel = lane & 48;
  float den = 0.f, a0 = 0.f, a1 = 0.f;

  for (int base = i0; base < i1; base += 16) {
    int i = base + (lane & 15);
    int s_ = 0;
    float w = 0.f;
    if (i < i1) {
      s_ = el[i];
      float lv = sdot[s_ * 4 + hB] + ddv;
      lv = fminf(fmaxf(lv, 0.2f * lv), 80.f);
      w = __expf(lv);
    }
    float g = w;
    g += __shfl_xor(g, 1);
    g += __shfl_xor(g, 2);
    g += __shfl_xor(g, 4);
    g += __shfl_xor(g, 8);
    den += g;

    const int rem = min(16, i1 - base);
    int j = 0;
    for (; j + 2 <= rem; j += 2) {
      int sA = __shfl(s_, j);
      int sB = __shfl(s_, j + 1);
      float wA = __shfl(w, wsel | j);
      float wB = __shfl(w, wsel | (j + 1));
      float2 hA = __half22float2(*(const __half2*)(hsrc + (size_t)sA * HIDn + lane * 2));
      float2 hBv = __half22float2(*(const __half2*)(hsrc + (size_t)sB * HIDn + lane * 2));
      a0 += hA.x * wA + hBv.x * wB;
      a1 += hA.y * wA + hBv.y * wB;
    }
    if (j < rem) {
      int sA = __shfl(s_, j);
      float wA = __shfl(w, wsel | j);
      float2 hA = __half22float2(*(const __half2*)(hsrc + (size_t)sA * HIDn + lane * 2));
      a0 += hA.x * wA;
      a1 += hA.y * wA;
    }
  }
  float dinv = __fdividef(1.f, den + 1e-16f);
  __half2 o2 = __floats2half2_rn(fmaxf(a0 * dinv, 0.f), fmaxf(a1 * dinv, 0.f));
  *(__half2*)(op.out + (size_t)dst * HIDn + lane * 2) = o2;
}

__global__ __launch_bounds__(256)
void csr_att3(EdgeOp op0, EdgeOp op1, EdgeOp op2, int Ndst)
{
  int wave = (blockIdx.x * 256 + threadIdx.x) >> 6;
  if (wave >= Ndst) return;
  const int lane = threadIdx.x & 63;
  if (blockIdx.y == 0)      csr_att_body(op0, wave, lane);
  else if (blockIdx.y == 1) csr_att_body(op1, wave, lane);
  else                      csr_att_body(op2, wave, lane);
}

// ---- fallback path (atomic scatter, fp32 h), used only if ws too small --
__global__ void edge_logit_max(const int* __restrict__ ei,
                               const float* __restrict__ sdot,
                               const float* __restrict__ ddot,
                               unsigned* __restrict__ m)
{
  int e = blockIdx.x * blockDim.x + threadIdx.x;
  if (e >= En) return;
  int s = ei[e], d = ei[En + e];
  #pragma unroll
  for (int hh = 0; hh < 4; ++hh) {
    float l = sdot[s * 4 + hh] + ddot[d * 4 + hh];
    l = (l > 0.f) ? l : 0.2f * l;
    atomicMax(&m[d * 4 + hh], fmap(l));
  }
}

__global__ void edge_exp_sum(const int* __restrict__ ei,
                             const float* __restrict__ sdot,
                             const float* __restrict__ ddot,
                             const unsigned* __restrict__ m,
                             float* __restrict__ sden,
                             float* __restrict__ ebuf)
{
  int e = blockIdx.x * blockDim.x + threadIdx.x;
  if (e >= En) return;
  int s = ei[e], d = ei[En + e];
  #pragma unroll
  for (int hh = 0; hh < 4; ++hh) {
    float l = sdot[s * 4 + hh] + ddot[d * 4 + hh];
    l = (l > 0.f) ? l : 0.2f * l;
    float ex = expf(fminf(l - fdecode(m[d * 4 + hh]), 0.f));
    ebuf[e * 4 + hh] = ex;
    atomicAdd(&sden[d * 4 + hh], ex);
  }
}

__global__ __launch_bounds__(256)
void edge_scatter(const int* __restrict__ ei, const float* __restrict__ hsrc,
                  const float* __restrict__ ebuf, const float* __restrict__ sden,
                  float* __restrict__ out)
{
  int gid  = blockIdx.x * 256 + threadIdx.x;
  int e    = gid >> 6;
  if (e >= En) return;
  int lane = gid & 63;
  int s = ei[e], d = ei[En + e];
  #pragma unroll
  for (int half = 0; half < 2; ++half) {
    int c  = lane + half * 64;
    int hh = c >> 5;
    float alpha = ebuf[e * 4 + hh] / (sden[d * 4 + hh] + 1e-16f);
    atomicAdd(&out[(size_t)d * HIDn + c], hsrc[(size_t)s * HIDn + c] * alpha);
  }
}

__global__ void relu_k(float* __restrict__ x, int n)
{
  int i = blockIdx.x * blockDim.x + threadIdx.x;
  if (i < n) x[i] = fmaxf(x[i], 0.f);
}

// ---- semantic-attention score via MFMA bf16 (fragment-ordered kWt) ------
template<int IN16>
__global__ __launch_bounds__(256)
void score_mfma(const void* __restrict__ oA, const void* __restrict__ oB,
                const unsigned short* __restrict__ kWt,
                const float* __restrict__ kb, const float* __restrict__ q,
                int N, float* __restrict__ slots)
{
  __shared__ float partw[4];
  const void* o = blockIdx.y ? oB : oA;
  const int tid = threadIdx.x;
  const int w = tid >> 6, lane = tid & 63;
  const int row0 = (blockIdx.x * 4 + w) * 16;
  const int m = lane & 15, b = lane >> 4;
  const int arow = row0 + m;
  const bool rok = arow < N;
  const bf16x8* WT = (const bf16x8*)kWt;

  const bf16x8 zfr = {0, 0, 0, 0, 0, 0, 0, 0};
  bf16x8 afr[4];
  {
    const size_t base = (size_t)arow * 128;
    #pragma unroll
    for (int ks = 0; ks < 4; ++ks) {
      if (rok) afr[ks] = packrow8<0, IN16>(o, nullptr, 0.f, 0.f, base + ks * 32 + b * 8);
      else     afr[ks] = zfr;
    }
  }

  float sum = 0.f;
  #pragma unroll
  for (int t = 0; t < 8; ++t) {
    f32x4 acc = {0.f, 0.f, 0.f, 0.f};
    const int col = t * 16 + m;
    #pragma unroll
    for (int ks = 0; ks < 4; ++ks)
      acc = __builtin_amdgcn_mfma_f32_16x16x32_bf16(afr[ks], WT[(t * 4 + ks) * 64 + lane], acc, 0, 0, 0);
    const float qc = q[col], kbc = kb[col];
    #pragma unroll
    for (int r = 0; r < 4; ++r) {
      int row = row0 + b * 4 + r;
      if (row < N) sum += qc * tanh_fast(acc[r] + kbc);
    }
  }
  #pragma unroll
  for (int off = 32; off > 0; off >>= 1) sum += __shfl_down(sum, off);
  if (lane == 0) partw[w] = sum;
  __syncthreads();
  if (tid == 0)
    atomicAdd(&slots[blockIdx.y],
              (partw[0] + partw[1] + partw[2] + partw[3]) * (1.f / (float)N));
}

__global__ void softmax2_kernel(float* sb)   // sb[0],sb[1] -> weights sb[2],sb[3]
{
  float s0 = sb[0], s1 = sb[1];
  float mx = fmaxf(s0, s1);
  float e0 = expf(s0 - mx), e1 = expf(s1 - mx);
  float inv = 1.f / (e0 + e1);
  sb[2] = e0 * inv;
  sb[3] = e1 * inv;
}

// ---- merged final projection via MFMA bf16 (fragment-ordered pWt) -------
template<int IN16>
__global__ __launch_bounds__(256)
void proj2_mfma(const void* __restrict__ fa, const void* __restrict__ fb,
                const float* __restrict__ wv, const void* __restrict__ fd,
                const unsigned short* __restrict__ pWt, const float* __restrict__ pb,
                float* __restrict__ outc, float* __restrict__ outd, int N)
{
  const bool isC = (blockIdx.y == 0);
  const int tid = threadIdx.x;
  const int w = tid >> 6, lane = tid & 63;
  const int row0 = (blockIdx.x * 4 + w) * 16;
  const int m = lane & 15, b = lane >> 4;
  const int arow = row0 + m;
  const bool rok = arow < N;
  float* out = isC ? outc : outd;
  const bf16x8* WT = (const bf16x8*)pWt;

  const bf16x8 zfr = {0, 0, 0, 0, 0, 0, 0, 0};
  bf16x8 afr[4];
  {
    const size_t base = (size_t)arow * 128;
    if (isC) {
      const float w2 = wv[2], w3 = wv[3];
      #pragma unroll
      for (int ks = 0; ks < 4; ++ks) {
        if (rok) afr[ks] = packrow8<2, IN16>(fa, fb, w2, w3, base + ks * 32 + b * 8);
        else     afr[ks] = zfr;
      }
    } else {
      #pragma unroll
      for (int ks = 0; ks < 4; ++ks) {
        if (rok) afr[ks] = packrow8<1, IN16>(fd, nullptr, 0.f, 0.f, base + ks * 32 + b * 8);
        else     afr[ks] = zfr;
      }
    }
  }

  f32x4 accs[4];
  float pbc[4];
  #pragma unroll
  for (int t = 0; t < 4; ++t) {
    f32x4 acc = {0.f, 0.f, 0.f, 0.f};
    const int col = t * 16 + m;
    #pragma unroll
    for (int ks = 0; ks < 4; ++ks)
      acc = __builtin_amdgcn_mfma_f32_16x16x32_bf16(afr[ks], WT[(t * 4 + ks) * 64 + lane], acc, 0, 0, 0);
    accs[t] = acc;
    pbc[t] = pb[col];
  }

  #pragma unroll
  for (int r = 0; r < 4; ++r) {
    const int row = row0 + b * 4 + r;
    float v[4];
    #pragma unroll
    for (int t = 0; t < 4; ++t) v[t] = accs[t][r] + pbc[t];
    if (isC) {
      float ss = v[0]*v[0] + v[1]*v[1] + v[2]*v[2] + v[3]*v[3];
      ss += __shfl_xor(ss, 1);
      ss += __shfl_xor(ss, 2);
      ss += __shfl_xor(ss, 4);
      ss += __shfl_xor(ss, 8);
      float inv = 1.f / fmaxf(sqrtf(ss), 1e-12f);
      #pragma unroll
      for (int t = 0; t < 4; ++t) v[t] *= inv;
    }
    if (row < N) {
      #pragma unroll
      for (int t = 0; t < 4; ++t)
        out[(size_t)row * OUTn + t * 16 + m] = v[t];
    }
  }
}

// ---- fallback edge-op dispatcher ----------------------------------------
static void run_edge_fb(hipStream_t stream, const int* ei,
                        const float* sdot, const float* ddot, const float* hsrc,
                        float* outb, int Ndst,
                        unsigned* mbuf, float* sden, float* ebuf)
{
  hipMemsetAsync(mbuf, 0, (size_t)Ndst * 4 * sizeof(unsigned), stream);
  edge_logit_max<<<(En + 255) / 256, 256, 0, stream>>>(ei, sdot, ddot, mbuf);
  hipMemsetAsync(sden, 0, (size_t)Ndst * 4 * sizeof(float), stream);
  edge_exp_sum<<<(En + 255) / 256, 256, 0, stream>>>(ei, sdot, ddot, mbuf, sden, ebuf);
  hipMemsetAsync(outb, 0, (size_t)Ndst * HIDn * sizeof(float), stream);
  edge_scatter<<<((size_t)En * 64 + 255) / 256, 256, 0, stream>>>(ei, hsrc, ebuf, sden, outb);
  relu_k<<<((size_t)Ndst * HIDn + 255) / 256, 256, 0, stream>>>(outb, Ndst * HIDn);
}

extern "C" void kernel_launch(void* const* d_in, const int* in_sizes, int n_in,
                              void* d_out, int out_size, void* d_ws, size_t ws_size,
                              hipStream_t stream)
{
  const float* xc    = (const float*)d_in[0];
  const float* xd    = (const float*)d_in[1];
  const int*   ei_cc = (const int*)d_in[2];
  const int*   ei_dc = (const int*)d_in[3];
  const int*   ei_cd = (const int*)d_in[4];
  const float* W1c = (const float*)d_in[5];  const float* b1c = (const float*)d_in[6];
  const float* W1d = (const float*)d_in[7];  const float* b1d = (const float*)d_in[8];
  const float* a1s_cc = (const float*)d_in[9];  const float* a1d_cc = (const float*)d_in[10];
  const float* a1s_dc = (const float*)d_in[11]; const float* a1d_dc = (const float*)d_in[12];
  const float* a1s_cd = (const float*)d_in[13]; const float* a1d_cd = (const float*)d_in[14];
  const float* k1W = (const float*)d_in[15]; const float* k1b = (const float*)d_in[16];
  const float* q1  = (const float*)d_in[17];
  const float* W2c = (const float*)d_in[18]; const float* b2c = (const float*)d_in[19];
  const float* W2d = (const float*)d_in[20]; const float* b2d = (const float*)d_in[21];
  const float* a2s_cc = (const float*)d_in[22]; const float* a2d_cc = (const float*)d_in[23];
  const float* a2s_dc = (const float*)d_in[24]; const float* a2d_dc = (const float*)d_in[25];
  const float* a2s_cd = (const float*)d_in[26]; const float* a2d_cd = (const float*)d_in[27];
  const float* k2W = (const float*)d_in[28]; const float* k2b = (const float*)d_in[29];
  const float* q2  = (const float*)d_in[30];
  const float* pW  = (const float*)d_in[31]; const float* pb  = (const float*)d_in[32];

  // ---------------- workspace layout ----------------
  float* ws = (float*)d_ws;
  const size_t NB = (size_t)NCn * HIDn;
  float* B0 = ws;            // node buffers (fp16 in CSR mode, fp32 fallback)
  float* B1 = ws + NB;
  float* B2 = ws + 2 * NB;
  float* B3 = ws + 3 * NB;
  float* B4 = ws + 4 * NB;
  float* sml = ws + 5 * NB;
  float* scc = sml;
  float* dcc = sml + 200000;
  float* ddc = sml + 400000;
  float* scd = sml + 600000;
  float* sdc = sml + 800000;
  float* dcd = sml + 1000000;
  float* scoreB = sml + 1200000;
  float* R0 = sml + 1200016;
  int*  R0i = (int*)R0;
  int*  offsBase  = R0i;                   // 150,004 ints (global offs)
  int*  elistBase = R0i + 150004;          // 1,200,000 ints (combined)
  int*  degBase   = R0i + 1350004;         // 150,000
  int*  cursorBase= R0i + 1500004;         // 150,000 (adjacent -> single memset)
  int*  inclBase  = R0i + 1650004;         // 150,000
  int*  bsumBase  = R0i + 1800004;         // 1,024
  unsigned short* kW1t = (unsigned short*)(R0i + 1801028);
  unsigned short* kW2t = (unsigned short*)(R0i + 1809220);
  unsigned short* pWt  = (unsigned short*)(R0i + 1817412);
  unsigned short* W1cH = (unsigned short*)(R0i + 1821508);
  unsigned short* W1cL = (unsigned short*)(R0i + 1837892);
  unsigned short* W1dH = (unsigned short*)(R0i + 1854276);
  unsigned short* W1dL = (unsigned short*)(R0i + 1870660);
  unsigned short* W2cH = (unsigned short*)(R0i + 1887044);
  unsigned short* W2cL = (unsigned short*)(R0i + 1895236);
  unsigned short* W2dH = (unsigned short*)(R0i + 1903428);
  unsigned short* W2dL = (unsigned short*)(R0i + 1911620);  // end 1,919,812 ints
  // fallback temps overlay (over CSR region)
  unsigned* mbuf = (unsigned*)R0;
  float*    sden = R0 + 200000;
  float*    ebuf = R0 + 400000;

  const size_t REQ_FLOATS = 5 * NB + 1200016 + 1919812;     // 35,119,828 fl = 140.5 MB
  const bool useCsr = ws_size >= REQ_FLOATS * sizeof(float);

  if (useCsr) {
    hipMemsetAsync(degBase, 0, 300000 * sizeof(int), stream);   // deg + cursor
    hist3<<<(3 * En + 255) / 256, 256, 0, stream>>>(ei_cc, ei_dc, ei_cd, degBase);
    scan_pass1<<<SCAN_NB, SCAN_BLK, 0, stream>>>(degBase, inclBase, bsumBase);
    scan_pass2<<<1, SCAN_BLK, 0, stream>>>(bsumBase, SCAN_NB);
    scan_pass3<<<SCAN_NB, SCAN_BLK, 0, stream>>>(inclBase, bsumBase, offsBase);
    fill3<<<(3 * En + 255) / 256, 256, 0, stream>>>(ei_cc, ei_dc, ei_cd,
                                                    offsBase, cursorBase, elistBase);
  }
  wprep<<<(139264 + 255) / 256, 256, 0, stream>>>(k1W, k2W, pW, W1c, W1d, W2c, W2d,
                                                  kW1t, kW2t, pWt,
                                                  W1cH, W1cL, W1dH, W1dL,
                                                  W2cH, W2cL, W2dH, W2dL);

  hipMemsetAsync(scoreB, 0, 8 * sizeof(float), stream);

  const int NT64 = (NCn + 63) / 64;
  const int NT128 = (NCn + 127) / 128;
  const int* offs0 = offsBase;
  const int* offs1 = offsBase + 50000;
  const int* offs2 = offsBase + 100000;

  auto edge_layer = [&](void* hc, void* hd, void* oCC, void* oDC, void* oCD) {
    if (useCsr) {
      EdgeOp o0{offs0, elistBase, scc, dcc, (const __half*)hc, (__half*)oCC};
      EdgeOp o1{offs1, elistBase, sdc, ddc, (const __half*)hd, (__half*)oDC};
      EdgeOp o2{offs2, elistBase, scd, dcd, (const __half*)hc, (__half*)oCD};
      csr_att3<<<dim3((NCn + 3) / 4, 3), 256, 0, stream>>>(o0, o1, o2, NCn);
    } else {
      run_edge_fb(stream, ei_cc, scc, dcc, (const float*)hc, (float*)oCC, NCn, mbuf, sden, ebuf);
      run_edge_fb(stream, ei_dc, sdc, ddc, (const float*)hd, (float*)oDC, NCn, mbuf, sden, ebuf);
      run_edge_fb(stream, ei_cd, scd, dcd, (const float*)hc, (float*)oCD, NDn, mbuf, sden, ebuf);
    }
  };

  if (useCsr) {
    // ---------------- layer 1 ----------------
    gemm2_mfma<256, 0, 0, 0, 1><<<dim3(NT128, 2), 256, 0, stream>>>(
        xc, nullptr, nullptr, W1cH, W1cL, b1c, B0,
        xd, W1dH, W1dL, b1d, B1, NCn,
        a1s_cc, a1d_cc, a1d_dc, a1s_cd, a1s_dc, a1d_cd,
        scc, dcc, ddc, scd, sdc, dcd);
    edge_layer(B0, B1, B2, B3, B4);
    score_mfma<1><<<dim3(NT64, 2), 256, 0, stream>>>(B2, B3, kW1t, k1b, q1, NCn, scoreB);
    softmax2_kernel<<<1, 1, 0, stream>>>(scoreB);

    // ---------------- layer 2 ----------------
    gemm2_mfma<128, 2, 1, 1, 1><<<dim3(NT128, 2), 256, 0, stream>>>(
        B2, B3, scoreB, W2cH, W2cL, b2c, B0,
        B4, W2dH, W2dL, b2d, B1, NCn,
        a2s_cc, a2d_cc, a2d_dc, a2s_cd, a2s_dc, a2d_cd,
        scc, dcc, ddc, scd, sdc, dcd);
    edge_layer(B0, B1, B2, B3, B4);
    score_mfma<1><<<dim3(NT64, 2), 256, 0, stream>>>(B2, B3, kW2t, k2b, q2, NCn, scoreB + 4);
    softmax2_kernel<<<1, 1, 0, stream>>>(scoreB + 4);

    // ---------------- projection (merged) ----------------
    proj2_mfma<1><<<dim3(NT64, 2), 256, 0, stream>>>(B2, B3, scoreB + 4, B4, pWt, pb,
                                                     (float*)d_out,
                                                     (float*)d_out + (size_t)NCn * OUTn, NCn);
  } else {
    // ---------------- fp32 fallback ----------------
    gemm2_mfma<256, 0, 0, 0, 0><<<dim3(NT128, 2), 256, 0, stream>>>(
        xc, nullptr, nullptr, W1cH, W1cL, b1c, B0,
        xd, W1dH, W1dL, b1d, B1, NCn,
        a1s_cc, a1d_cc, a1d_dc, a1s_cd, a1s_dc, a1d_cd,
        scc, dcc, ddc, scd, sdc, dcd);
    edge_layer(B0, B1, B2, B3, B4);
    score_mfma<0><<<dim3(NT64, 2), 256, 0, stream>>>(B2, B3, kW1t, k1b, q1, NCn, scoreB);
    softmax2_kernel<<<1, 1, 0, stream>>>(scoreB);

    gemm2_mfma<128, 2, 1, 0, 0><<<dim3(NT128, 2), 256, 0, stream>>>(
        B2, B3, scoreB, W2cH, W2cL, b2c, B0,
        B4, W2dH, W2dL, b2d, B1, NCn,
        a2s_cc, a2d_cc, a2d_dc, a2s_cd, a2s_dc, a2d_cd,
        scc, dcc, ddc, scd, sdc, dcd);
    edge_layer(B0, B1, B2, B3, B4);
    score_mfma<0><<<dim3(NT64, 2), 256, 0, stream>>>(B2, B3, kW2t, k2b, q2, NCn, scoreB + 4);
    softmax2_kernel<<<1, 1, 0, stream>>>(scoreB + 4);

    proj2_mfma<0><<<dim3(NT64, 2), 256, 0, stream>>>(B2, B3, scoreB + 4, B4, pWt, pb,
                                                     (float*)d_out,
                                                     (float*)d_out + (size_t)NCn * OUTn, NCn);
  }
}

// Round 27
// 427.929 us; speedup vs baseline: 1.1390x; 1.1390x over previous
//
#include <hip/hip_runtime.h>
#include <hip/hip_fp16.h>
#include <cmath>

#define DEVI static __device__ __forceinline__

constexpr int HIDn = 128, OUTn = 64;
constexpr int NCn = 50000, NDn = 50000, En = 400000;
constexpr int SCAN_N = 150000, SCAN_BLK = 1024;
constexpr int SCAN_NB = (SCAN_N + SCAN_BLK - 1) / SCAN_BLK;   // 147

typedef __attribute__((ext_vector_type(8))) short bf16x8;
typedef __attribute__((ext_vector_type(4))) float f32x4;

// monotonic float->uint mapping for atomicMax on floats (handles signs)
DEVI unsigned fmap(float f) {
  int i = __float_as_int(f);
  return (i < 0) ? ~((unsigned)i) : (((unsigned)i) | 0x80000000u);
}
DEVI float fdecode(unsigned u) {
  int i = (u & 0x80000000u) ? (int)(u & 0x7fffffffu) : (int)(~u);
  return __int_as_float(i);
}

DEVI float tanh_fast(float x) {           // 1 - 2/(e^{2x}+1); saturates correctly
  float e = __expf(2.f * x);
  return 1.f - __fdividef(2.f, e + 1.f);
}

DEVI unsigned short f2bf(float x) {       // fp32 -> bf16 RNE
  unsigned u = __float_as_uint(x);
  return (unsigned short)((u + 0x7FFFu + ((u >> 16) & 1u)) >> 16);
}
DEVI float bf2f(unsigned short h) {
  unsigned u = ((unsigned)h) << 16;
  return __uint_as_float(u);
}

// ---- vectorized 8-wide A-row load + fused transform (value-based) -------
// MODE: 0=plain, 1=elu(x), 2=elu(w2*a+w3*b). HALF: input dtype fp16.
template<int MODE, int HALF>
DEVI void loadrow8(float* __restrict__ tmp,
                   const void* __restrict__ A, const void* __restrict__ A2,
                   float w2, float w3, size_t base)
{
  float v[8];
  if (HALF) {
    float4 raw = *(const float4*)((const __half*)A + base);
    const __half2* h2 = (const __half2*)&raw;
    #pragma unroll
    for (int j = 0; j < 4; ++j) {
      float2 f = __half22float2(h2[j]);
      v[2 * j] = f.x; v[2 * j + 1] = f.y;
    }
  } else {
    const float4* p = (const float4*)((const float*)A + base);
    float4 u0 = p[0], u1 = p[1];
    v[0] = u0.x; v[1] = u0.y; v[2] = u0.z; v[3] = u0.w;
    v[4] = u1.x; v[5] = u1.y; v[6] = u1.z; v[7] = u1.w;
  }
  if (MODE == 2) {
    float vb[8];
    if (HALF) {
      float4 raw = *(const float4*)((const __half*)A2 + base);
      const __half2* h2 = (const __half2*)&raw;
      #pragma unroll
      for (int j = 0; j < 4; ++j) {
        float2 f = __half22float2(h2[j]);
        vb[2 * j] = f.x; vb[2 * j + 1] = f.y;
      }
    } else {
      const float4* q = (const float4*)((const float*)A2 + base);
      float4 t0 = q[0], t1 = q[1];
      vb[0] = t0.x; vb[1] = t0.y; vb[2] = t0.z; vb[3] = t0.w;
      vb[4] = t1.x; vb[5] = t1.y; vb[6] = t1.z; vb[7] = t1.w;
    }
    #pragma unroll
    for (int i = 0; i < 8; ++i) v[i] = w2 * v[i] + w3 * vb[i];
  }
  if (MODE >= 1) {
    #pragma unroll
    for (int i = 0; i < 8; ++i) v[i] = (v[i] > 0.f) ? v[i] : (__expf(v[i]) - 1.f);
  }
  #pragma unroll
  for (int i = 0; i < 8; ++i) tmp[i] = v[i];
}

template<int MODE, int HALF>
DEVI bf16x8 packrow8(const void* __restrict__ A, const void* __restrict__ A2,
                     float w2, float w3, size_t base)
{
  float t[8];
  loadrow8<MODE, HALF>(t, A, A2, w2, w3, base);
  bf16x8 r;
  #pragma unroll
  for (int i = 0; i < 8; ++i) r[i] = (short)f2bf(t[i]);
  return r;
}

// ====== merged MFMA GEMM (c & d paths) + fused attention dots ============
// B pre-arranged in FRAGMENT ORDER and staged per-chunk in LDS (linear ->
// coalesced staging, conflict-free ds_read_b128, shared by all 4 waves).
// A staged in LDS with pad 44; prefetch issued BEFORE the barrier.
template<int KI, int MODEc, int MODEd, int IN16, int OUT16>
__global__ __launch_bounds__(256)
void gemm2_mfma(const void* __restrict__ Ac, const void* __restrict__ Ac2,
                const float* __restrict__ wv,
                const unsigned short* __restrict__ WcH, const unsigned short* __restrict__ WcL,
                const float* __restrict__ bc, void* __restrict__ Cc,
                const void* __restrict__ Ad,
                const unsigned short* __restrict__ WdH, const unsigned short* __restrict__ WdL,
                const float* __restrict__ bd, void* __restrict__ Cd,
                int N,
                const float* __restrict__ avc0, const float* __restrict__ avc1,
                const float* __restrict__ avc2, const float* __restrict__ avc3,
                const float* __restrict__ avd0, const float* __restrict__ avd1,
                float* __restrict__ doc0, float* __restrict__ doc1,
                float* __restrict__ doc2, float* __restrict__ doc3,
                float* __restrict__ dod0, float* __restrict__ dod1)
{
  __shared__ float As[64][44];                 // 11.3 KB, stride 44 -> 2-way banks
  __shared__ unsigned short BhS[4096];         // 8 KB (one chunk, fragment order)
  __shared__ unsigned short BlS[4096];         // 8 KB
  constexpr int NC = KI / 32;
  const bool isC = (blockIdx.y == 0);
  const void* A  = isC ? Ac : Ad;
  const void* A2 = isC ? Ac2 : nullptr;
  const unsigned short* WH = isC ? WcH : WdH;
  const unsigned short* WL = isC ? WcL : WdL;
  const float* bias = isC ? bc : bd;
  void* Cv = isC ? Cc : Cd;
  float w2 = 0.f, w3 = 0.f;
  if (MODEc == 2) { if (isC) { w2 = wv[2]; w3 = wv[3]; } }

  const int tid = threadIdx.x;
  const int w = tid >> 6, lane = tid & 63;
  const int m = lane & 15, b4 = lane >> 4;
  const int row0 = blockIdx.x * 64;
  const int row0w = row0 + w * 16;

  // staging thread roles
  const int rA = tid >> 2, kqA = (tid & 3) << 3;
  const int rowA = row0 + rA;

  f32x4 acc[8];
  #pragma unroll
  for (int t = 0; t < 8; ++t) acc[t] = (f32x4){0.f, 0.f, 0.f, 0.f};

  float tA[8];
  float4 rbh0, rbh1, rbl0, rbl1;   // 16 ushorts per plane per thread

  auto loadA = [&](int k0) {
    if (rowA < N) {
      if (isC) loadrow8<MODEc, IN16>(tA, A, A2, w2, w3, (size_t)rowA * KI + k0 + kqA);
      else     loadrow8<MODEd, IN16>(tA, A, nullptr, 0.f, 0.f, (size_t)rowA * KI + k0 + kqA);
    } else {
      #pragma unroll
      for (int i = 0; i < 8; ++i) tA[i] = 0.f;
    }
  };
  auto loadB = [&](int c) {
    const float4* ph = (const float4*)(WH + (size_t)c * 4096 + tid * 16);
    const float4* pl = (const float4*)(WL + (size_t)c * 4096 + tid * 16);
    rbh0 = ph[0]; rbh1 = ph[1];
    rbl0 = pl[0]; rbl1 = pl[1];
  };

  loadA(0);
  loadB(0);

  for (int c = 0; c < NC; ++c) {
    // write staged regs to LDS (all linear/coalesced)
    *(float4*)&As[rA][kqA]     = make_float4(tA[0], tA[1], tA[2], tA[3]);
    *(float4*)&As[rA][kqA + 4] = make_float4(tA[4], tA[5], tA[6], tA[7]);
    *(float4*)&BhS[tid * 16]     = rbh0;
    *(float4*)&BhS[tid * 16 + 8] = rbh1;
    *(float4*)&BlS[tid * 16]     = rbl0;
    *(float4*)&BlS[tid * 16 + 8] = rbl1;

    // prefetch next chunk BEFORE the barrier (regs already consumed)
    if (c + 1 < NC) { loadA((c + 1) * 32); loadB(c + 1); }
    __syncthreads();

    bf16x8 ah, al;
    {
      const float* ap = &As[w * 16 + m][b4 * 8];
      float4 u0 = *(const float4*)ap;
      float4 u1 = *(const float4*)(ap + 4);
      float t8[8] = {u0.x, u0.y, u0.z, u0.w, u1.x, u1.y, u1.z, u1.w};
      #pragma unroll
      for (int i = 0; i < 8; ++i) {
        unsigned short h = f2bf(t8[i]);
        ah[i] = (short)h;
        al[i] = (short)f2bf(t8[i] - bf2f(h));
      }
    }
    #pragma unroll
    for (int t = 0; t < 8; ++t) {
      const int fi = (t * 64 + lane) * 8;
      bf16x8 bh = *(const bf16x8*)&BhS[fi];
      bf16x8 bl = *(const bf16x8*)&BlS[fi];
      acc[t] = __builtin_amdgcn_mfma_f32_16x16x32_bf16(ah, bh, acc[t], 0, 0, 0);
      acc[t] = __builtin_amdgcn_mfma_f32_16x16x32_bf16(al, bh, acc[t], 0, 0, 0);
      acc[t] = __builtin_amdgcn_mfma_f32_16x16x32_bf16(ah, bl, acc[t], 0, 0, 0);
    }
    __syncthreads();
  }

  // ---- epilogue: bias + C store ----
  float bt[8];
  #pragma unroll
  for (int t = 0; t < 8; ++t) bt[t] = bias[t * 16 + m];

  #pragma unroll
  for (int t = 0; t < 8; ++t) {
    const int col = t * 16 + m;
    #pragma unroll
    for (int r = 0; r < 4; ++r) {
      const int row = row0w + b4 * 4 + r;
      if (row < N) {
        float v = acc[t][r] + bt[t];
        if (OUT16) ((__half*)Cv)[(size_t)row * 128 + col] = __float2half(v);
        else       ((float*)Cv)[(size_t)row * 128 + col] = v;
      }
    }
  }

  // ---- fused attention dots: per (row, head) reduce over 16 m-lanes ----
  const float* avp[4];
  float* dop[4];
  int nv;
  if (isC) {
    avp[0] = avc0; avp[1] = avc1; avp[2] = avc2; avp[3] = avc3;
    dop[0] = doc0; dop[1] = doc1; dop[2] = doc2; dop[3] = doc3; nv = 4;
  } else {
    avp[0] = avd0; avp[1] = avd1; avp[2] = avd0; avp[3] = avd1;
    dop[0] = dod0; dop[1] = dod1; dop[2] = dod0; dop[3] = dod1; nv = 2;
  }
  float avv[4][8];
  #pragma unroll
  for (int v = 0; v < 4; ++v) {
    if (v < nv) {
      #pragma unroll
      for (int t = 0; t < 8; ++t) avv[v][t] = avp[v][t * 16 + m];
    }
  }
  #pragma unroll
  for (int h = 0; h < 4; ++h) {
    #pragma unroll
    for (int v = 0; v < 4; ++v) {
      if (v < nv) {
        #pragma unroll
        for (int r = 0; r < 4; ++r) {
          float p = (acc[2 * h][r] + bt[2 * h]) * avv[v][2 * h]
                  + (acc[2 * h + 1][r] + bt[2 * h + 1]) * avv[v][2 * h + 1];
          p += __shfl_xor(p, 1);
          p += __shfl_xor(p, 2);
          p += __shfl_xor(p, 4);
          p += __shfl_xor(p, 8);
          if (m == 0) {
            const int row = row0w + b4 * 4 + r;
            if (row < N) dop[v][(size_t)row * 4 + h] = p;
          }
        }
      }
    }
  }
}

// ================= CSR build: hist + 3-pass scan + fill ==================
__global__ void hist3(const int* __restrict__ ei0, const int* __restrict__ ei1,
                      const int* __restrict__ ei2, int* __restrict__ deg)
{
  int gid = blockIdx.x * blockDim.x + threadIdx.x;
  if (gid >= 3 * En) return;
  int g = gid / En, e = gid - g * En;
  const int* ei = (g == 0) ? ei0 : (g == 1) ? ei1 : ei2;
  atomicAdd(&deg[g * 50000 + ei[En + e]], 1);
}

__global__ void scan_pass1(const int* __restrict__ deg, int* __restrict__ incl,
                           int* __restrict__ bsum)
{
  __shared__ int wsum[16];
  int tid = threadIdx.x;
  int gid = blockIdx.x * SCAN_BLK + tid;
  int v = (gid < SCAN_N) ? deg[gid] : 0;
  int lane = tid & 63, w = tid >> 6;
  int x = v;
  #pragma unroll
  for (int off = 1; off < 64; off <<= 1) {
    int y = __shfl_up(x, off);
    if (lane >= off) x += y;
  }
  if (lane == 63) wsum[w] = x;
  __syncthreads();
  if (tid == 0) {
    int s = 0;
    #pragma unroll
    for (int ww = 0; ww < 16; ++ww) { int t = wsum[ww]; wsum[ww] = s; s += t; }
    bsum[blockIdx.x] = s;
  }
  __syncthreads();
  x += wsum[w];
  if (gid < SCAN_N) incl[gid] = x;
}

__global__ void scan_pass2(int* __restrict__ bsum, int nb)
{
  __shared__ int wsum[16];
  int tid = threadIdx.x;
  int v = (tid < nb) ? bsum[tid] : 0;
  int lane = tid & 63, w = tid >> 6;
  int x = v;
  #pragma unroll
  for (int off = 1; off < 64; off <<= 1) {
    int y = __shfl_up(x, off);
    if (lane >= off) x += y;
  }
  if (lane == 63) wsum[w] = x;
  __syncthreads();
  if (tid == 0) {
    int s = 0;
    #pragma unroll
    for (int ww = 0; ww < 16; ++ww) { int t = wsum[ww]; wsum[ww] = s; s += t; }
  }
  __syncthreads();
  x += wsum[w];
  if (tid < nb) bsum[tid] = x - v;
}

__global__ void scan_pass3(const int* __restrict__ incl, const int* __restrict__ bsum,
                           int* __restrict__ offs)
{
  int gid = blockIdx.x * SCAN_BLK + threadIdx.x;
  if (gid == 0) offs[0] = 0;
  if (gid < SCAN_N) offs[gid + 1] = incl[gid] + bsum[gid / SCAN_BLK];
}

__global__ void fill3(const int* __restrict__ ei0, const int* __restrict__ ei1,
                      const int* __restrict__ ei2, const int* __restrict__ offs,
                      int* __restrict__ cursor, int* __restrict__ elist)
{
  int gid = blockIdx.x * blockDim.x + threadIdx.x;
  if (gid >= 3 * En) return;
  int g = gid / En, e = gid - g * En;
  const int* ei = (g == 0) ? ei0 : (g == 1) ? ei1 : ei2;
  int s = ei[e], d = g * 50000 + ei[En + e];
  int p = atomicAdd(&cursor[d], 1);
  elist[offs[d] + p] = s;
}

// ---- weight prep: all B operands in MFMA fragment order -----------------
__global__ void wprep(const float* __restrict__ k1W, const float* __restrict__ k2W,
                      const float* __restrict__ pW,
                      const float* __restrict__ W1c, const float* __restrict__ W1d,
                      const float* __restrict__ W2c, const float* __restrict__ W2d,
                      unsigned short* kW1t, unsigned short* kW2t, unsigned short* pWt,
                      unsigned short* W1cH, unsigned short* W1cL,
                      unsigned short* W1dH, unsigned short* W1dL,
                      unsigned short* W2cH, unsigned short* W2cL,
                      unsigned short* W2dH, unsigned short* W2dL)
{
  int gid = blockIdx.x * 256 + threadIdx.x;
  if (gid < 16384) {                       // k1W: 128x128
    int i = gid, k = i >> 7, col = i & 127;
    int ks = k >> 5, b4 = (k >> 3) & 3, j = k & 7, t = col >> 4, m = col & 15;
    kW1t[(size_t)(((t * 4 + ks) * 64) + m + 16 * b4) * 8 + j] = f2bf(k1W[i]);
  } else if (gid < 32768) {                // k2W: 128x128
    int i = gid - 16384, k = i >> 7, col = i & 127;
    int ks = k >> 5, b4 = (k >> 3) & 3, j = k & 7, t = col >> 4, m = col & 15;
    kW2t[(size_t)(((t * 4 + ks) * 64) + m + 16 * b4) * 8 + j] = f2bf(k2W[i]);
  } else if (gid < 40960) {                // pW: 128x64
    int i = gid - 32768, k = i / 64, col = i - k * 64;
    int ks = k >> 5, b4 = (k >> 3) & 3, j = k & 7, t = col >> 4, m = col & 15;
    pWt[(size_t)(((t * 4 + ks) * 64) + m + 16 * b4) * 8 + j] = f2bf(pW[i]);
  } else if (gid < 73728) {                // W1c: 256x128
    int i = gid - 40960, k = i >> 7, col = i & 127;
    int c = k >> 5, b4 = (k >> 3) & 3, j = k & 7, t = col >> 4, m = col & 15;
    size_t f = (size_t)(((c * 8 + t) * 64) + m + 16 * b4) * 8 + j;
    float v = W1c[i]; unsigned short h = f2bf(v);
    W1cH[f] = h; W1cL[f] = f2bf(v - bf2f(h));
  } else if (gid < 106496) {               // W1d: 256x128
    int i = gid - 73728, k = i >> 7, col = i & 127;
    int c = k >> 5, b4 = (k >> 3) & 3, j = k & 7, t = col >> 4, m = col & 15;
    size_t f = (size_t)(((c * 8 + t) * 64) + m + 16 * b4) * 8 + j;
    float v = W1d[i]; unsigned short h = f2bf(v);
    W1dH[f] = h; W1dL[f] = f2bf(v - bf2f(h));
  } else if (gid < 122880) {               // W2c: 128x128
    int i = gid - 106496, k = i >> 7, col = i & 127;
    int c = k >> 5, b4 = (k >> 3) & 3, j = k & 7, t = col >> 4, m = col & 15;
    size_t f = (size_t)(((c * 8 + t) * 64) + m + 16 * b4) * 8 + j;
    float v = W2c[i]; unsigned short h = f2bf(v);
    W2cH[f] = h; W2cL[f] = f2bf(v - bf2f(h));
  } else if (gid < 139264) {               // W2d: 128x128
    int i = gid - 122880, k = i >> 7, col = i & 127;
    int c = k >> 5, b4 = (k >> 3) & 3, j = k & 7, t = col >> 4, m = col & 15;
    size_t f = (size_t)(((c * 8 + t) * 64) + m + 16 * b4) * 8 + j;
    float v = W2d[i]; unsigned short h = f2bf(v);
    W2dH[f] = h; W2dL[f] = f2bf(v - bf2f(h));
  }
}

// ==== FUSED edge attention (CSR, fp16 h, float4 gather) ==================
// Wave = one dst. Weight phase: lane = (head g=lane>>4, edge slot l=lane&15).
// Aggregation: lane = (edge group g, column sixteenth l); each lane loads a
// 16B float4 of the source row -> 4 edges per load instruction (4x fewer
// VMEM ops, 4x fewer shuffles than half2 gather). Strided edge->group
// mapping j=g+4k balances the mean-degree-8 tail.
struct EdgeOp {
  const int* offs; const int* elist;
  const float* sdot; const float* ddot;
  const __half* hsrc; __half* out;
};

DEVI void csr_att_body(const EdgeOp& op, int dst, int lane)
{
  const int i0 = op.offs[dst], i1 = op.offs[dst + 1];
  const int g  = lane >> 4;          // weight phase: head; agg phase: edge group
  const int l  = lane & 15;          // weight phase: edge slot; agg: col sixteenth
  const int hc = l >> 2;             // head owning cols l*8..l*8+7
  const float ddv = op.ddot[dst * 4 + g];
  const __half* hsrc = op.hsrc;
  const float* sdot = op.sdot;
  const int* el = op.elist;
  float den = 0.f;
  float acc[8] = {0.f, 0.f, 0.f, 0.f, 0.f, 0.f, 0.f, 0.f};

  for (int base = i0; base < i1; base += 16) {
    int i = base + l;
    int s_ = 0;
    float w = 0.f;
    if (i < i1) {
      s_ = el[i];
      float lv = sdot[s_ * 4 + g] + ddv;
      lv = fminf(fmaxf(lv, 0.2f * lv), 80.f);
      w = __expf(lv);
    }
    float gs = w;
    gs += __shfl_xor(gs, 1);
    gs += __shfl_xor(gs, 2);
    gs += __shfl_xor(gs, 4);
    gs += __shfl_xor(gs, 8);
    den += gs;

    const int rem = min(16, i1 - base);
    const int nk = (rem + 3) >> 2;
    for (int k = 0; k < nk; ++k) {
      const int j = g + 4 * k;                       // j<16; invalid j has w=0,s=0
      int sj = __shfl(s_, j);
      float wj = __shfl(w, hc * 16 + j);
      float4 hv = *(const float4*)(hsrc + (size_t)sj * HIDn + l * 8);
      const __half2* h2 = (const __half2*)&hv;
      #pragma unroll
      for (int q = 0; q < 4; ++q) {
        float2 f = __half22float2(h2[q]);
        acc[2 * q]     += f.x * wj;
        acc[2 * q + 1] += f.y * wj;
      }
    }
  }

  // reduce partial sums across the 4 edge groups
  #pragma unroll
  for (int q = 0; q < 8; ++q) {
    acc[q] += __shfl_xor(acc[q], 16);
    acc[q] += __shfl_xor(acc[q], 32);
  }
  float dv = __shfl(den, hc * 16);
  float dinv = __fdividef(1.f, dv + 1e-16f);
  if (lane < 16) {
    __half2 o[4];
    #pragma unroll
    for (int q = 0; q < 4; ++q)
      o[q] = __floats2half2_rn(fmaxf(acc[2 * q] * dinv, 0.f),
                               fmaxf(acc[2 * q + 1] * dinv, 0.f));
    *(float4*)(op.out + (size_t)dst * HIDn + l * 8) = *(const float4*)o;
  }
}

__global__ __launch_bounds__(256)
void csr_att3(EdgeOp op0, EdgeOp op1, EdgeOp op2, int Ndst)
{
  int wave = (blockIdx.x * 256 + threadIdx.x) >> 6;
  if (wave >= Ndst) return;
  const int lane = threadIdx.x & 63;
  if (blockIdx.y == 0)      csr_att_body(op0, wave, lane);
  else if (blockIdx.y == 1) csr_att_body(op1, wave, lane);
  else                      csr_att_body(op2, wave, lane);
}

// ---- fallback path (atomic scatter, fp32 h), used only if ws too small --
__global__ void edge_logit_max(const int* __restrict__ ei,
                               const float* __restrict__ sdot,
                               const float* __restrict__ ddot,
                               unsigned* __restrict__ m)
{
  int e = blockIdx.x * blockDim.x + threadIdx.x;
  if (e >= En) return;
  int s = ei[e], d = ei[En + e];
  #pragma unroll
  for (int hh = 0; hh < 4; ++hh) {
    float l = sdot[s * 4 + hh] + ddot[d * 4 + hh];
    l = (l > 0.f) ? l : 0.2f * l;
    atomicMax(&m[d * 4 + hh], fmap(l));
  }
}

__global__ void edge_exp_sum(const int* __restrict__ ei,
                             const float* __restrict__ sdot,
                             const float* __restrict__ ddot,
                             const unsigned* __restrict__ m,
                             float* __restrict__ sden,
                             float* __restrict__ ebuf)
{
  int e = blockIdx.x * blockDim.x + threadIdx.x;
  if (e >= En) return;
  int s = ei[e], d = ei[En + e];
  #pragma unroll
  for (int hh = 0; hh < 4; ++hh) {
    float l = sdot[s * 4 + hh] + ddot[d * 4 + hh];
    l = (l > 0.f) ? l : 0.2f * l;
    float ex = expf(fminf(l - fdecode(m[d * 4 + hh]), 0.f));
    ebuf[e * 4 + hh] = ex;
    atomicAdd(&sden[d * 4 + hh], ex);
  }
}

__global__ __launch_bounds__(256)
void edge_scatter(const int* __restrict__ ei, const float* __restrict__ hsrc,
                  const float* __restrict__ ebuf, const float* __restrict__ sden,
                  float* __restrict__ out)
{
  int gid  = blockIdx.x * 256 + threadIdx.x;
  int e    = gid >> 6;
  if (e >= En) return;
  int lane = gid & 63;
  int s = ei[e], d = ei[En + e];
  #pragma unroll
  for (int half = 0; half < 2; ++half) {
    int c  = lane + half * 64;
    int hh = c >> 5;
    float alpha = ebuf[e * 4 + hh] / (sden[d * 4 + hh] + 1e-16f);
    atomicAdd(&out[(size_t)d * HIDn + c], hsrc[(size_t)s * HIDn + c] * alpha);
  }
}

__global__ void relu_k(float* __restrict__ x, int n)
{
  int i = blockIdx.x * blockDim.x + threadIdx.x;
  if (i < n) x[i] = fmaxf(x[i], 0.f);
}

// ---- semantic-attention score via MFMA bf16 (fragment-ordered kWt) ------
template<int IN16>
__global__ __launch_bounds__(256)
void score_mfma(const void* __restrict__ oA, const void* __restrict__ oB,
                const unsigned short* __restrict__ kWt,
                const float* __restrict__ kb, const float* __restrict__ q,
                int N, float* __restrict__ slots)
{
  __shared__ float partw[4];
  const void* o = blockIdx.y ? oB : oA;
  const int tid = threadIdx.x;
  const int w = tid >> 6, lane = tid & 63;
  const int row0 = (blockIdx.x * 4 + w) * 16;
  const int m = lane & 15, b = lane >> 4;
  const int arow = row0 + m;
  const bool rok = arow < N;
  const bf16x8* WT = (const bf16x8*)kWt;

  const bf16x8 zfr = {0, 0, 0, 0, 0, 0, 0, 0};
  bf16x8 afr[4];
  {
    const size_t base = (size_t)arow * 128;
    #pragma unroll
    for (int ks = 0; ks < 4; ++ks) {
      if (rok) afr[ks] = packrow8<0, IN16>(o, nullptr, 0.f, 0.f, base + ks * 32 + b * 8);
      else     afr[ks] = zfr;
    }
  }

  float sum = 0.f;
  #pragma unroll
  for (int t = 0; t < 8; ++t) {
    f32x4 acc = {0.f, 0.f, 0.f, 0.f};
    const int col = t * 16 + m;
    #pragma unroll
    for (int ks = 0; ks < 4; ++ks)
      acc = __builtin_amdgcn_mfma_f32_16x16x32_bf16(afr[ks], WT[(t * 4 + ks) * 64 + lane], acc, 0, 0, 0);
    const float qc = q[col], kbc = kb[col];
    #pragma unroll
    for (int r = 0; r < 4; ++r) {
      int row = row0 + b * 4 + r;
      if (row < N) sum += qc * tanh_fast(acc[r] + kbc);
    }
  }
  #pragma unroll
  for (int off = 32; off > 0; off >>= 1) sum += __shfl_down(sum, off);
  if (lane == 0) partw[w] = sum;
  __syncthreads();
  if (tid == 0)
    atomicAdd(&slots[blockIdx.y],
              (partw[0] + partw[1] + partw[2] + partw[3]) * (1.f / (float)N));
}

__global__ void softmax2_kernel(float* sb)   // sb[0],sb[1] -> weights sb[2],sb[3]
{
  float s0 = sb[0], s1 = sb[1];
  float mx = fmaxf(s0, s1);
  float e0 = expf(s0 - mx), e1 = expf(s1 - mx);
  float inv = 1.f / (e0 + e1);
  sb[2] = e0 * inv;
  sb[3] = e1 * inv;
}

// ---- merged final projection via MFMA bf16 (fragment-ordered pWt) -------
template<int IN16>
__global__ __launch_bounds__(256)
void proj2_mfma(const void* __restrict__ fa, const void* __restrict__ fb,
                const float* __restrict__ wv, const void* __restrict__ fd,
                const unsigned short* __restrict__ pWt, const float* __restrict__ pb,
                float* __restrict__ outc, float* __restrict__ outd, int N)
{
  const bool isC = (blockIdx.y == 0);
  const int tid = threadIdx.x;
  const int w = tid >> 6, lane = tid & 63;
  const int row0 = (blockIdx.x * 4 + w) * 16;
  const int m = lane & 15, b = lane >> 4;
  const int arow = row0 + m;
  const bool rok = arow < N;
  float* out = isC ? outc : outd;
  const bf16x8* WT = (const bf16x8*)pWt;

  const bf16x8 zfr = {0, 0, 0, 0, 0, 0, 0, 0};
  bf16x8 afr[4];
  {
    const size_t base = (size_t)arow * 128;
    if (isC) {
      const float w2 = wv[2], w3 = wv[3];
      #pragma unroll
      for (int ks = 0; ks < 4; ++ks) {
        if (rok) afr[ks] = packrow8<2, IN16>(fa, fb, w2, w3, base + ks * 32 + b * 8);
        else     afr[ks] = zfr;
      }
    } else {
      #pragma unroll
      for (int ks = 0; ks < 4; ++ks) {
        if (rok) afr[ks] = packrow8<1, IN16>(fd, nullptr, 0.f, 0.f, base + ks * 32 + b * 8);
        else     afr[ks] = zfr;
      }
    }
  }

  f32x4 accs[4];
  float pbc[4];
  #pragma unroll
  for (int t = 0; t < 4; ++t) {
    f32x4 acc = {0.f, 0.f, 0.f, 0.f};
    const int col = t * 16 + m;
    #pragma unroll
    for (int ks = 0; ks < 4; ++ks)
      acc = __builtin_amdgcn_mfma_f32_16x16x32_bf16(afr[ks], WT[(t * 4 + ks) * 64 + lane], acc, 0, 0, 0);
    accs[t] = acc;
    pbc[t] = pb[col];
  }

  #pragma unroll
  for (int r = 0; r < 4; ++r) {
    const int row = row0 + b * 4 + r;
    float v[4];
    #pragma unroll
    for (int t = 0; t < 4; ++t) v[t] = accs[t][r] + pbc[t];
    if (isC) {
      float ss = v[0]*v[0] + v[1]*v[1] + v[2]*v[2] + v[3]*v[3];
      ss += __shfl_xor(ss, 1);
      ss += __shfl_xor(ss, 2);
      ss += __shfl_xor(ss, 4);
      ss += __shfl_xor(ss, 8);
      float inv = 1.f / fmaxf(sqrtf(ss), 1e-12f);
      #pragma unroll
      for (int t = 0; t < 4; ++t) v[t] *= inv;
    }
    if (row < N) {
      #pragma unroll
      for (int t = 0; t < 4; ++t)
        out[(size_t)row * OUTn + t * 16 + m] = v[t];
    }
  }
}

// ---- fallback edge-op dispatcher ----------------------------------------
static void run_edge_fb(hipStream_t stream, const int* ei,
                        const float* sdot, const float* ddot, const float* hsrc,
                        float* outb, int Ndst,
                        unsigned* mbuf, float* sden, float* ebuf)
{
  hipMemsetAsync(mbuf, 0, (size_t)Ndst * 4 * sizeof(unsigned), stream);
  edge_logit_max<<<(En + 255) / 256, 256, 0, stream>>>(ei, sdot, ddot, mbuf);
  hipMemsetAsync(sden, 0, (size_t)Ndst * 4 * sizeof(float), stream);
  edge_exp_sum<<<(En + 255) / 256, 256, 0, stream>>>(ei, sdot, ddot, mbuf, sden, ebuf);
  hipMemsetAsync(outb, 0, (size_t)Ndst * HIDn * sizeof(float), stream);
  edge_scatter<<<((size_t)En * 64 + 255) / 256, 256, 0, stream>>>(ei, hsrc, ebuf, sden, outb);
  relu_k<<<((size_t)Ndst * HIDn + 255) / 256, 256, 0, stream>>>(outb, Ndst * HIDn);
}

extern "C" void kernel_launch(void* const* d_in, const int* in_sizes, int n_in,
                              void* d_out, int out_size, void* d_ws, size_t ws_size,
                              hipStream_t stream)
{
  const float* xc    = (const float*)d_in[0];
  const float* xd    = (const float*)d_in[1];
  const int*   ei_cc = (const int*)d_in[2];
  const int*   ei_dc = (const int*)d_in[3];
  const int*   ei_cd = (const int*)d_in[4];
  const float* W1c = (const float*)d_in[5];  const float* b1c = (const float*)d_in[6];
  const float* W1d = (const float*)d_in[7];  const float* b1d = (const float*)d_in[8];
  const float* a1s_cc = (const float*)d_in[9];  const float* a1d_cc = (const float*)d_in[10];
  const float* a1s_dc = (const float*)d_in[11]; const float* a1d_dc = (const float*)d_in[12];
  const float* a1s_cd = (const float*)d_in[13]; const float* a1d_cd = (const float*)d_in[14];
  const float* k1W = (const float*)d_in[15]; const float* k1b = (const float*)d_in[16];
  const float* q1  = (const float*)d_in[17];
  const float* W2c = (const float*)d_in[18]; const float* b2c = (const float*)d_in[19];
  const float* W2d = (const float*)d_in[20]; const float* b2d = (const float*)d_in[21];
  const float* a2s_cc = (const float*)d_in[22]; const float* a2d_cc = (const float*)d_in[23];
  const float* a2s_dc = (const float*)d_in[24]; const float* a2d_dc = (const float*)d_in[25];
  const float* a2s_cd = (const float*)d_in[26]; const float* a2d_cd = (const float*)d_in[27];
  const float* k2W = (const float*)d_in[28]; const float* k2b = (const float*)d_in[29];
  const float* q2  = (const float*)d_in[30];
  const float* pW  = (const float*)d_in[31]; const float* pb  = (const float*)d_in[32];

  // ---------------- workspace layout ----------------
  float* ws = (float*)d_ws;
  const size_t NB = (size_t)NCn * HIDn;
  float* B0 = ws;            // node buffers (fp16 in CSR mode, fp32 fallback)
  float* B1 = ws + NB;
  float* B2 = ws + 2 * NB;
  float* B3 = ws + 3 * NB;
  float* B4 = ws + 4 * NB;
  float* sml = ws + 5 * NB;
  float* scc = sml;
  float* dcc = sml + 200000;
  float* ddc = sml + 400000;
  float* scd = sml + 600000;
  float* sdc = sml + 800000;
  float* dcd = sml + 1000000;
  float* scoreB = sml + 1200000;
  float* R0 = sml + 1200016;
  int*  R0i = (int*)R0;
  int*  offsBase  = R0i;                   // 150,004 ints (global offs)
  int*  elistBase = R0i + 150004;          // 1,200,000 ints (combined)
  int*  degBase   = R0i + 1350004;         // 150,000
  int*  cursorBase= R0i + 1500004;         // 150,000 (adjacent -> single memset)
  int*  inclBase  = R0i + 1650004;         // 150,000
  int*  bsumBase  = R0i + 1800004;         // 1,024
  unsigned short* kW1t = (unsigned short*)(R0i + 1801028);
  unsigned short* kW2t = (unsigned short*)(R0i + 1809220);
  unsigned short* pWt  = (unsigned short*)(R0i + 1817412);
  unsigned short* W1cH = (unsigned short*)(R0i + 1821508);
  unsigned short* W1cL = (unsigned short*)(R0i + 1837892);
  unsigned short* W1dH = (unsigned short*)(R0i + 1854276);
  unsigned short* W1dL = (unsigned short*)(R0i + 1870660);
  unsigned short* W2cH = (unsigned short*)(R0i + 1887044);
  unsigned short* W2cL = (unsigned short*)(R0i + 1895236);
  unsigned short* W2dH = (unsigned short*)(R0i + 1903428);
  unsigned short* W2dL = (unsigned short*)(R0i + 1911620);  // end 1,919,812 ints
  // fallback temps overlay (over CSR region)
  unsigned* mbuf = (unsigned*)R0;
  float*    sden = R0 + 200000;
  float*    ebuf = R0 + 400000;

  const size_t REQ_FLOATS = 5 * NB + 1200016 + 1919812;     // 35,119,828 fl = 140.5 MB
  const bool useCsr = ws_size >= REQ_FLOATS * sizeof(float);

  if (useCsr) {
    hipMemsetAsync(degBase, 0, 300000 * sizeof(int), stream);   // deg + cursor
    hist3<<<(3 * En + 255) / 256, 256, 0, stream>>>(ei_cc, ei_dc, ei_cd, degBase);
    scan_pass1<<<SCAN_NB, SCAN_BLK, 0, stream>>>(degBase, inclBase, bsumBase);
    scan_pass2<<<1, SCAN_BLK, 0, stream>>>(bsumBase, SCAN_NB);
    scan_pass3<<<SCAN_NB, SCAN_BLK, 0, stream>>>(inclBase, bsumBase, offsBase);
    fill3<<<(3 * En + 255) / 256, 256, 0, stream>>>(ei_cc, ei_dc, ei_cd,
                                                    offsBase, cursorBase, elistBase);
  }
  wprep<<<(139264 + 255) / 256, 256, 0, stream>>>(k1W, k2W, pW, W1c, W1d, W2c, W2d,
                                                  kW1t, kW2t, pWt,
                                                  W1cH, W1cL, W1dH, W1dL,
                                                  W2cH, W2cL, W2dH, W2dL);

  hipMemsetAsync(scoreB, 0, 8 * sizeof(float), stream);

  const int NT64 = (NCn + 63) / 64;
  const int* offs0 = offsBase;
  const int* offs1 = offsBase + 50000;
  const int* offs2 = offsBase + 100000;

  auto edge_layer = [&](void* hc, void* hd, void* oCC, void* oDC, void* oCD) {
    if (useCsr) {
      EdgeOp o0{offs0, elistBase, scc, dcc, (const __half*)hc, (__half*)oCC};
      EdgeOp o1{offs1, elistBase, sdc, ddc, (const __half*)hd, (__half*)oDC};
      EdgeOp o2{offs2, elistBase, scd, dcd, (const __half*)hc, (__half*)oCD};
      csr_att3<<<dim3((NCn + 3) / 4, 3), 256, 0, stream>>>(o0, o1, o2, NCn);
    } else {
      run_edge_fb(stream, ei_cc, scc, dcc, (const float*)hc, (float*)oCC, NCn, mbuf, sden, ebuf);
      run_edge_fb(stream, ei_dc, sdc, ddc, (const float*)hd, (float*)oDC, NCn, mbuf, sden, ebuf);
      run_edge_fb(stream, ei_cd, scd, dcd, (const float*)hc, (float*)oCD, NDn, mbuf, sden, ebuf);
    }
  };

  if (useCsr) {
    // ---------------- layer 1 ----------------
    gemm2_mfma<256, 0, 0, 0, 1><<<dim3(NT64, 2), 256, 0, stream>>>(
        xc, nullptr, nullptr, W1cH, W1cL, b1c, B0,
        xd, W1dH, W1dL, b1d, B1, NCn,
        a1s_cc, a1d_cc, a1d_dc, a1s_cd, a1s_dc, a1d_cd,
        scc, dcc, ddc, scd, sdc, dcd);
    edge_layer(B0, B1, B2, B3, B4);
    score_mfma<1><<<dim3(NT64, 2), 256, 0, stream>>>(B2, B3, kW1t, k1b, q1, NCn, scoreB);
    softmax2_kernel<<<1, 1, 0, stream>>>(scoreB);

    // ---------------- layer 2 ----------------
    gemm2_mfma<128, 2, 1, 1, 1><<<dim3(NT64, 2), 256, 0, stream>>>(
        B2, B3, scoreB, W2cH, W2cL, b2c, B0,
        B4, W2dH, W2dL, b2d, B1, NCn,
        a2s_cc, a2d_cc, a2d_dc, a2s_cd, a2s_dc, a2d_cd,
        scc, dcc, ddc, scd, sdc, dcd);
    edge_layer(B0, B1, B2, B3, B4);
    score_mfma<1><<<dim3(NT64, 2), 256, 0, stream>>>(B2, B3, kW2t, k2b, q2, NCn, scoreB + 4);
    softmax2_kernel<<<1, 1, 0, stream>>>(scoreB + 4);

    // ---------------- projection (merged) ----------------
    proj2_mfma<1><<<dim3(NT64, 2), 256, 0, stream>>>(B2, B3, scoreB + 4, B4, pWt, pb,
                                                     (float*)d_out,
                                                     (float*)d_out + (size_t)NCn * OUTn, NCn);
  } else {
    // ---------------- fp32 fallback ----------------
    gemm2_mfma<256, 0, 0, 0, 0><<<dim3(NT64, 2), 256, 0, stream>>>(
        xc, nullptr, nullptr, W1cH, W1cL, b1c, B0,
        xd, W1dH, W1dL, b1d, B1, NCn,
        a1s_cc, a1d_cc, a1d_dc, a1s_cd, a1s_dc, a1d_cd,
        scc, dcc, ddc, scd, sdc, dcd);
    edge_layer(B0, B1, B2, B3, B4);
    score_mfma<0><<<dim3(NT64, 2), 256, 0, stream>>>(B2, B3, kW1t, k1b, q1, NCn, scoreB);
    softmax2_kernel<<<1, 1, 0, stream>>>(scoreB);

    gemm2_mfma<128, 2, 1, 0, 0><<<dim3(NT64, 2), 256, 0, stream>>>(
        B2, B3, scoreB, W2cH, W2cL, b2c, B0,
        B4, W2dH, W2dL, b2d, B1, NCn,
        a2s_cc, a2d_cc, a2d_dc, a2s_cd, a2s_dc, a2d_cd,
        scc, dcc, ddc, scd, sdc, dcd);
    edge_layer(B0, B1, B2, B3, B4);
    score_mfma<0><<<dim3(NT64, 2), 256, 0, stream>>>(B2, B3, kW2t, k2b, q2, NCn, scoreB + 4);
    softmax2_kernel<<<1, 1, 0, stream>>>(scoreB + 4);

    proj2_mfma<0><<<dim3(NT64, 2), 256, 0, stream>>>(B2, B3, scoreB + 4, B4, pWt, pb,
                                                     (float*)d_out,
                                                     (float*)d_out + (size_t)NCn * OUTn, NCn);
  }
}

// Round 28
// 423.266 us; speedup vs baseline: 1.1516x; 1.0110x over previous
//
#include <hip/hip_runtime.h>
#include <hip/hip_fp16.h>
#include <cmath>

#define DEVI static __device__ __forceinline__

constexpr int HIDn = 128, OUTn = 64;
constexpr int NCn = 50000, NDn = 50000, En = 400000;
constexpr int SCAN_N = 150000, SCAN_BLK = 1024;
constexpr int SCAN_NB = (SCAN_N + SCAN_BLK - 1) / SCAN_BLK;   // 147

typedef __attribute__((ext_vector_type(8))) _Float16 fp16x8;
typedef __attribute__((ext_vector_type(4))) float f32x4;

// monotonic float->uint mapping for atomicMax on floats (handles signs)
DEVI unsigned fmap(float f) {
  int i = __float_as_int(f);
  return (i < 0) ? ~((unsigned)i) : (((unsigned)i) | 0x80000000u);
}
DEVI float fdecode(unsigned u) {
  int i = (u & 0x80000000u) ? (int)(u & 0x7fffffffu) : (int)(~u);
  return __int_as_float(i);
}

DEVI float tanh_fast(float x) {           // 1 - 2/(e^{2x}+1); saturates correctly
  float e = __expf(2.f * x);
  return 1.f - __fdividef(2.f, e + 1.f);
}

DEVI unsigned short f2h(float x) {        // fp32 -> fp16 RNE (bit pattern)
  _Float16 h = (_Float16)x;
  return *(unsigned short*)&h;
}

// ---- vectorized 8-wide A-row load + fused transform (value-based) -------
// MODE: 0=plain, 1=elu(x), 2=elu(w2*a+w3*b). HALF: input dtype fp16.
template<int MODE, int HALF>
DEVI void loadrow8(float* __restrict__ tmp,
                   const void* __restrict__ A, const void* __restrict__ A2,
                   float w2, float w3, size_t base)
{
  float v[8];
  if (HALF) {
    float4 raw = *(const float4*)((const __half*)A + base);
    const __half2* h2 = (const __half2*)&raw;
    #pragma unroll
    for (int j = 0; j < 4; ++j) {
      float2 f = __half22float2(h2[j]);
      v[2 * j] = f.x; v[2 * j + 1] = f.y;
    }
  } else {
    const float4* p = (const float4*)((const float*)A + base);
    float4 u0 = p[0], u1 = p[1];
    v[0] = u0.x; v[1] = u0.y; v[2] = u0.z; v[3] = u0.w;
    v[4] = u1.x; v[5] = u1.y; v[6] = u1.z; v[7] = u1.w;
  }
  if (MODE == 2) {
    float vb[8];
    if (HALF) {
      float4 raw = *(const float4*)((const __half*)A2 + base);
      const __half2* h2 = (const __half2*)&raw;
      #pragma unroll
      for (int j = 0; j < 4; ++j) {
        float2 f = __half22float2(h2[j]);
        vb[2 * j] = f.x; vb[2 * j + 1] = f.y;
      }
    } else {
      const float4* q = (const float4*)((const float*)A2 + base);
      float4 t0 = q[0], t1 = q[1];
      vb[0] = t0.x; vb[1] = t0.y; vb[2] = t0.z; vb[3] = t0.w;
      vb[4] = t1.x; vb[5] = t1.y; vb[6] = t1.z; vb[7] = t1.w;
    }
    #pragma unroll
    for (int i = 0; i < 8; ++i) v[i] = w2 * v[i] + w3 * vb[i];
  }
  if (MODE >= 1) {
    #pragma unroll
    for (int i = 0; i < 8; ++i) v[i] = (v[i] > 0.f) ? v[i] : (__expf(v[i]) - 1.f);
  }
  #pragma unroll
  for (int i = 0; i < 8; ++i) tmp[i] = v[i];
}

template<int MODE, int HALF>
DEVI fp16x8 packrow8h(const void* __restrict__ A, const void* __restrict__ A2,
                      float w2, float w3, size_t base)
{
  if (HALF && MODE == 0) {                // fp16 input, no transform: direct bits
    float4 raw = *(const float4*)((const __half*)A + base);
    return *(const fp16x8*)&raw;
  }
  float t[8];
  loadrow8<MODE, HALF>(t, A, A2, w2, w3, base);
  fp16x8 r;
  #pragma unroll
  for (int i = 0; i < 8; ++i) r[i] = (_Float16)t[i];
  return r;
}

// ====== merged MFMA GEMM (c & d paths) + fused attention dots ============
// fp16 MFMA (1 per fragment vs 3 bf16 hi/lo): single B plane in fragment
// order, staged per-chunk in LDS; A staged in LDS (pad 44); register
// prefetch issued before the barrier (round-23 schedule).
template<int KI, int MODEc, int MODEd, int IN16, int OUT16>
__global__ __launch_bounds__(256)
void gemm2_mfma(const void* __restrict__ Ac, const void* __restrict__ Ac2,
                const float* __restrict__ wv,
                const unsigned short* __restrict__ WcH, const unsigned short* __restrict__ WcL,
                const float* __restrict__ bc, void* __restrict__ Cc,
                const void* __restrict__ Ad,
                const unsigned short* __restrict__ WdH, const unsigned short* __restrict__ WdL,
                const float* __restrict__ bd, void* __restrict__ Cd,
                int N,
                const float* __restrict__ avc0, const float* __restrict__ avc1,
                const float* __restrict__ avc2, const float* __restrict__ avc3,
                const float* __restrict__ avd0, const float* __restrict__ avd1,
                float* __restrict__ doc0, float* __restrict__ doc1,
                float* __restrict__ doc2, float* __restrict__ doc3,
                float* __restrict__ dod0, float* __restrict__ dod1)
{
  __shared__ float As[64][44];                 // 11.3 KB, stride 44 -> 2-way banks
  __shared__ unsigned short BhS[4096];         // 8 KB (one chunk, fragment order)
  constexpr int NC = KI / 32;
  const bool isC = (blockIdx.y == 0);
  const void* A  = isC ? Ac : Ad;
  const void* A2 = isC ? Ac2 : nullptr;
  const unsigned short* WH = isC ? WcH : WdH;
  const float* bias = isC ? bc : bd;
  void* Cv = isC ? Cc : Cd;
  float w2 = 0.f, w3 = 0.f;
  if (MODEc == 2) { if (isC) { w2 = wv[2]; w3 = wv[3]; } }

  const int tid = threadIdx.x;
  const int w = tid >> 6, lane = tid & 63;
  const int m = lane & 15, b4 = lane >> 4;
  const int row0 = blockIdx.x * 64;
  const int row0w = row0 + w * 16;

  // staging thread roles
  const int rA = tid >> 2, kqA = (tid & 3) << 3;
  const int rowA = row0 + rA;

  f32x4 acc[8];
  #pragma unroll
  for (int t = 0; t < 8; ++t) acc[t] = (f32x4){0.f, 0.f, 0.f, 0.f};

  float tA[8];
  float4 rbh0, rbh1;               // 16 ushorts (one fp16 plane) per thread

  auto loadA = [&](int k0) {
    if (rowA < N) {
      if (isC) loadrow8<MODEc, IN16>(tA, A, A2, w2, w3, (size_t)rowA * KI + k0 + kqA);
      else     loadrow8<MODEd, IN16>(tA, A, nullptr, 0.f, 0.f, (size_t)rowA * KI + k0 + kqA);
    } else {
      #pragma unroll
      for (int i = 0; i < 8; ++i) tA[i] = 0.f;
    }
  };
  auto loadB = [&](int c) {
    const float4* ph = (const float4*)(WH + (size_t)c * 4096 + tid * 16);
    rbh0 = ph[0]; rbh1 = ph[1];
  };

  loadA(0);
  loadB(0);

  for (int c = 0; c < NC; ++c) {
    // write staged regs to LDS (all linear/coalesced)
    *(float4*)&As[rA][kqA]     = make_float4(tA[0], tA[1], tA[2], tA[3]);
    *(float4*)&As[rA][kqA + 4] = make_float4(tA[4], tA[5], tA[6], tA[7]);
    *(float4*)&BhS[tid * 16]     = rbh0;
    *(float4*)&BhS[tid * 16 + 8] = rbh1;

    // prefetch next chunk BEFORE the barrier (regs already consumed)
    if (c + 1 < NC) { loadA((c + 1) * 32); loadB(c + 1); }
    __syncthreads();

    fp16x8 ah;
    {
      const float* ap = &As[w * 16 + m][b4 * 8];
      float4 u0 = *(const float4*)ap;
      float4 u1 = *(const float4*)(ap + 4);
      float t8[8] = {u0.x, u0.y, u0.z, u0.w, u1.x, u1.y, u1.z, u1.w};
      #pragma unroll
      for (int i = 0; i < 8; ++i) ah[i] = (_Float16)t8[i];
    }
    #pragma unroll
    for (int t = 0; t < 8; ++t) {
      const int fi = (t * 64 + lane) * 8;
      fp16x8 bh = *(const fp16x8*)&BhS[fi];
      acc[t] = __builtin_amdgcn_mfma_f32_16x16x32_f16(ah, bh, acc[t], 0, 0, 0);
    }
    __syncthreads();
  }

  // ---- epilogue: bias + C store ----
  float bt[8];
  #pragma unroll
  for (int t = 0; t < 8; ++t) bt[t] = bias[t * 16 + m];

  #pragma unroll
  for (int t = 0; t < 8; ++t) {
    const int col = t * 16 + m;
    #pragma unroll
    for (int r = 0; r < 4; ++r) {
      const int row = row0w + b4 * 4 + r;
      if (row < N) {
        float v = acc[t][r] + bt[t];
        if (OUT16) ((__half*)Cv)[(size_t)row * 128 + col] = __float2half(v);
        else       ((float*)Cv)[(size_t)row * 128 + col] = v;
      }
    }
  }

  // ---- fused attention dots: per (row, head) reduce over 16 m-lanes ----
  const float* avp[4];
  float* dop[4];
  int nv;
  if (isC) {
    avp[0] = avc0; avp[1] = avc1; avp[2] = avc2; avp[3] = avc3;
    dop[0] = doc0; dop[1] = doc1; dop[2] = doc2; dop[3] = doc3; nv = 4;
  } else {
    avp[0] = avd0; avp[1] = avd1; avp[2] = avd0; avp[3] = avd1;
    dop[0] = dod0; dop[1] = dod1; dop[2] = dod0; dop[3] = dod1; nv = 2;
  }
  float avv[4][8];
  #pragma unroll
  for (int v = 0; v < 4; ++v) {
    if (v < nv) {
      #pragma unroll
      for (int t = 0; t < 8; ++t) avv[v][t] = avp[v][t * 16 + m];
    }
  }
  #pragma unroll
  for (int h = 0; h < 4; ++h) {
    #pragma unroll
    for (int v = 0; v < 4; ++v) {
      if (v < nv) {
        #pragma unroll
        for (int r = 0; r < 4; ++r) {
          float p = (acc[2 * h][r] + bt[2 * h]) * avv[v][2 * h]
                  + (acc[2 * h + 1][r] + bt[2 * h + 1]) * avv[v][2 * h + 1];
          p += __shfl_xor(p, 1);
          p += __shfl_xor(p, 2);
          p += __shfl_xor(p, 4);
          p += __shfl_xor(p, 8);
          if (m == 0) {
            const int row = row0w + b4 * 4 + r;
            if (row < N) dop[v][(size_t)row * 4 + h] = p;
          }
        }
      }
    }
  }
}

// ================= CSR build: hist + 3-pass scan + fill ==================
__global__ void hist3(const int* __restrict__ ei0, const int* __restrict__ ei1,
                      const int* __restrict__ ei2, int* __restrict__ deg)
{
  int gid = blockIdx.x * blockDim.x + threadIdx.x;
  if (gid >= 3 * En) return;
  int g = gid / En, e = gid - g * En;
  const int* ei = (g == 0) ? ei0 : (g == 1) ? ei1 : ei2;
  atomicAdd(&deg[g * 50000 + ei[En + e]], 1);
}

__global__ void scan_pass1(const int* __restrict__ deg, int* __restrict__ incl,
                           int* __restrict__ bsum)
{
  __shared__ int wsum[16];
  int tid = threadIdx.x;
  int gid = blockIdx.x * SCAN_BLK + tid;
  int v = (gid < SCAN_N) ? deg[gid] : 0;
  int lane = tid & 63, w = tid >> 6;
  int x = v;
  #pragma unroll
  for (int off = 1; off < 64; off <<= 1) {
    int y = __shfl_up(x, off);
    if (lane >= off) x += y;
  }
  if (lane == 63) wsum[w] = x;
  __syncthreads();
  if (tid == 0) {
    int s = 0;
    #pragma unroll
    for (int ww = 0; ww < 16; ++ww) { int t = wsum[ww]; wsum[ww] = s; s += t; }
    bsum[blockIdx.x] = s;
  }
  __syncthreads();
  x += wsum[w];
  if (gid < SCAN_N) incl[gid] = x;
}

__global__ void scan_pass2(int* __restrict__ bsum, int nb)
{
  __shared__ int wsum[16];
  int tid = threadIdx.x;
  int v = (tid < nb) ? bsum[tid] : 0;
  int lane = tid & 63, w = tid >> 6;
  int x = v;
  #pragma unroll
  for (int off = 1; off < 64; off <<= 1) {
    int y = __shfl_up(x, off);
    if (lane >= off) x += y;
  }
  if (lane == 63) wsum[w] = x;
  __syncthreads();
  if (tid == 0) {
    int s = 0;
    #pragma unroll
    for (int ww = 0; ww < 16; ++ww) { int t = wsum[ww]; wsum[ww] = s; s += t; }
  }
  __syncthreads();
  x += wsum[w];
  if (tid < nb) bsum[tid] = x - v;
}

__global__ void scan_pass3(const int* __restrict__ incl, const int* __restrict__ bsum,
                           int* __restrict__ offs)
{
  int gid = blockIdx.x * SCAN_BLK + threadIdx.x;
  if (gid == 0) offs[0] = 0;
  if (gid < SCAN_N) offs[gid + 1] = incl[gid] + bsum[gid / SCAN_BLK];
}

__global__ void fill3(const int* __restrict__ ei0, const int* __restrict__ ei1,
                      const int* __restrict__ ei2, const int* __restrict__ offs,
                      int* __restrict__ cursor, int* __restrict__ elist)
{
  int gid = blockIdx.x * blockDim.x + threadIdx.x;
  if (gid >= 3 * En) return;
  int g = gid / En, e = gid - g * En;
  const int* ei = (g == 0) ? ei0 : (g == 1) ? ei1 : ei2;
  int s = ei[e], d = g * 50000 + ei[En + e];
  int p = atomicAdd(&cursor[d], 1);
  elist[offs[d] + p] = s;
}

// ---- weight prep: all B operands in MFMA fragment order, fp16 ----------
__global__ void wprep(const float* __restrict__ k1W, const float* __restrict__ k2W,
                      const float* __restrict__ pW,
                      const float* __restrict__ W1c, const float* __restrict__ W1d,
                      const float* __restrict__ W2c, const float* __restrict__ W2d,
                      unsigned short* kW1t, unsigned short* kW2t, unsigned short* pWt,
                      unsigned short* W1cH, unsigned short* W1cL,
                      unsigned short* W1dH, unsigned short* W1dL,
                      unsigned short* W2cH, unsigned short* W2cL,
                      unsigned short* W2dH, unsigned short* W2dL)
{
  int gid = blockIdx.x * 256 + threadIdx.x;
  if (gid < 16384) {                       // k1W: 128x128
    int i = gid, k = i >> 7, col = i & 127;
    int ks = k >> 5, b4 = (k >> 3) & 3, j = k & 7, t = col >> 4, m = col & 15;
    kW1t[(size_t)(((t * 4 + ks) * 64) + m + 16 * b4) * 8 + j] = f2h(k1W[i]);
  } else if (gid < 32768) {                // k2W: 128x128
    int i = gid - 16384, k = i >> 7, col = i & 127;
    int ks = k >> 5, b4 = (k >> 3) & 3, j = k & 7, t = col >> 4, m = col & 15;
    kW2t[(size_t)(((t * 4 + ks) * 64) + m + 16 * b4) * 8 + j] = f2h(k2W[i]);
  } else if (gid < 40960) {                // pW: 128x64
    int i = gid - 32768, k = i / 64, col = i - k * 64;
    int ks = k >> 5, b4 = (k >> 3) & 3, j = k & 7, t = col >> 4, m = col & 15;
    pWt[(size_t)(((t * 4 + ks) * 64) + m + 16 * b4) * 8 + j] = f2h(pW[i]);
  } else if (gid < 73728) {                // W1c: 256x128
    int i = gid - 40960, k = i >> 7, col = i & 127;
    int c = k >> 5, b4 = (k >> 3) & 3, j = k & 7, t = col >> 4, m = col & 15;
    size_t f = (size_t)(((c * 8 + t) * 64) + m + 16 * b4) * 8 + j;
    W1cH[f] = f2h(W1c[i]);
  } else if (gid < 106496) {               // W1d: 256x128
    int i = gid - 73728, k = i >> 7, col = i & 127;
    int c = k >> 5, b4 = (k >> 3) & 3, j = k & 7, t = col >> 4, m = col & 15;
    size_t f = (size_t)(((c * 8 + t) * 64) + m + 16 * b4) * 8 + j;
    W1dH[f] = f2h(W1d[i]);
  } else if (gid < 122880) {               // W2c: 128x128
    int i = gid - 106496, k = i >> 7, col = i & 127;
    int c = k >> 5, b4 = (k >> 3) & 3, j = k & 7, t = col >> 4, m = col & 15;
    size_t f = (size_t)(((c * 8 + t) * 64) + m + 16 * b4) * 8 + j;
    W2cH[f] = f2h(W2c[i]);
  } else if (gid < 139264) {               // W2d: 128x128
    int i = gid - 122880, k = i >> 7, col = i & 127;
    int c = k >> 5, b4 = (k >> 3) & 3, j = k & 7, t = col >> 4, m = col & 15;
    size_t f = (size_t)(((c * 8 + t) * 64) + m + 16 * b4) * 8 + j;
    W2dH[f] = f2h(W2d[i]);
  }
}

// ==== FUSED edge attention (CSR, fp16 h, float4 gather) ==================
struct EdgeOp {
  const int* offs; const int* elist;
  const float* sdot; const float* ddot;
  const __half* hsrc; __half* out;
};

DEVI void csr_att_body(const EdgeOp& op, int dst, int lane)
{
  const int i0 = op.offs[dst], i1 = op.offs[dst + 1];
  const int g  = lane >> 4;          // weight phase: head; agg phase: edge group
  const int l  = lane & 15;          // weight phase: edge slot; agg: col sixteenth
  const int hc = l >> 2;             // head owning cols l*8..l*8+7
  const float ddv = op.ddot[dst * 4 + g];
  const __half* hsrc = op.hsrc;
  const float* sdot = op.sdot;
  const int* el = op.elist;
  float den = 0.f;
  float acc[8] = {0.f, 0.f, 0.f, 0.f, 0.f, 0.f, 0.f, 0.f};

  for (int base = i0; base < i1; base += 16) {
    int i = base + l;
    int s_ = 0;
    float w = 0.f;
    if (i < i1) {
      s_ = el[i];
      float lv = sdot[s_ * 4 + g] + ddv;
      lv = fminf(fmaxf(lv, 0.2f * lv), 80.f);
      w = __expf(lv);
    }
    float gs = w;
    gs += __shfl_xor(gs, 1);
    gs += __shfl_xor(gs, 2);
    gs += __shfl_xor(gs, 4);
    gs += __shfl_xor(gs, 8);
    den += gs;

    const int rem = min(16, i1 - base);
    const int nk = (rem + 3) >> 2;
    for (int k = 0; k < nk; ++k) {
      const int j = g + 4 * k;                       // j<16; invalid j has w=0,s=0
      int sj = __shfl(s_, j);
      float wj = __shfl(w, hc * 16 + j);
      float4 hv = *(const float4*)(hsrc + (size_t)sj * HIDn + l * 8);
      const __half2* h2 = (const __half2*)&hv;
      #pragma unroll
      for (int q = 0; q < 4; ++q) {
        float2 f = __half22float2(h2[q]);
        acc[2 * q]     += f.x * wj;
        acc[2 * q + 1] += f.y * wj;
      }
    }
  }

  // reduce partial sums across the 4 edge groups
  #pragma unroll
  for (int q = 0; q < 8; ++q) {
    acc[q] += __shfl_xor(acc[q], 16);
    acc[q] += __shfl_xor(acc[q], 32);
  }
  float dv = __shfl(den, hc * 16);
  float dinv = __fdividef(1.f, dv + 1e-16f);
  if (lane < 16) {
    __half2 o[4];
    #pragma unroll
    for (int q = 0; q < 4; ++q)
      o[q] = __floats2half2_rn(fmaxf(acc[2 * q] * dinv, 0.f),
                               fmaxf(acc[2 * q + 1] * dinv, 0.f));
    *(float4*)(op.out + (size_t)dst * HIDn + l * 8) = *(const float4*)o;
  }
}

__global__ __launch_bounds__(256)
void csr_att3(EdgeOp op0, EdgeOp op1, EdgeOp op2, int Ndst)
{
  int wave = (blockIdx.x * 256 + threadIdx.x) >> 6;
  if (wave >= Ndst) return;
  const int lane = threadIdx.x & 63;
  if (blockIdx.y == 0)      csr_att_body(op0, wave, lane);
  else if (blockIdx.y == 1) csr_att_body(op1, wave, lane);
  else                      csr_att_body(op2, wave, lane);
}

// ---- fallback path (atomic scatter, fp32 h), used only if ws too small --
__global__ void edge_logit_max(const int* __restrict__ ei,
                               const float* __restrict__ sdot,
                               const float* __restrict__ ddot,
                               unsigned* __restrict__ m)
{
  int e = blockIdx.x * blockDim.x + threadIdx.x;
  if (e >= En) return;
  int s = ei[e], d = ei[En + e];
  #pragma unroll
  for (int hh = 0; hh < 4; ++hh) {
    float l = sdot[s * 4 + hh] + ddot[d * 4 + hh];
    l = (l > 0.f) ? l : 0.2f * l;
    atomicMax(&m[d * 4 + hh], fmap(l));
  }
}

__global__ void edge_exp_sum(const int* __restrict__ ei,
                             const float* __restrict__ sdot,
                             const float* __restrict__ ddot,
                             const unsigned* __restrict__ m,
                             float* __restrict__ sden,
                             float* __restrict__ ebuf)
{
  int e = blockIdx.x * blockDim.x + threadIdx.x;
  if (e >= En) return;
  int s = ei[e], d = ei[En + e];
  #pragma unroll
  for (int hh = 0; hh < 4; ++hh) {
    float l = sdot[s * 4 + hh] + ddot[d * 4 + hh];
    l = (l > 0.f) ? l : 0.2f * l;
    float ex = expf(fminf(l - fdecode(m[d * 4 + hh]), 0.f));
    ebuf[e * 4 + hh] = ex;
    atomicAdd(&sden[d * 4 + hh], ex);
  }
}

__global__ __launch_bounds__(256)
void edge_scatter(const int* __restrict__ ei, const float* __restrict__ hsrc,
                  const float* __restrict__ ebuf, const float* __restrict__ sden,
                  float* __restrict__ out)
{
  int gid  = blockIdx.x * 256 + threadIdx.x;
  int e    = gid >> 6;
  if (e >= En) return;
  int lane = gid & 63;
  int s = ei[e], d = ei[En + e];
  #pragma unroll
  for (int half = 0; half < 2; ++half) {
    int c  = lane + half * 64;
    int hh = c >> 5;
    float alpha = ebuf[e * 4 + hh] / (sden[d * 4 + hh] + 1e-16f);
    atomicAdd(&out[(size_t)d * HIDn + c], hsrc[(size_t)s * HIDn + c] * alpha);
  }
}

__global__ void relu_k(float* __restrict__ x, int n)
{
  int i = blockIdx.x * blockDim.x + threadIdx.x;
  if (i < n) x[i] = fmaxf(x[i], 0.f);
}

// ---- semantic-attention score via MFMA fp16 (fragment-ordered kWt) ------
template<int IN16>
__global__ __launch_bounds__(256)
void score_mfma(const void* __restrict__ oA, const void* __restrict__ oB,
                const unsigned short* __restrict__ kWt,
                const float* __restrict__ kb, const float* __restrict__ q,
                int N, float* __restrict__ slots)
{
  __shared__ float partw[4];
  const void* o = blockIdx.y ? oB : oA;
  const int tid = threadIdx.x;
  const int w = tid >> 6, lane = tid & 63;
  const int row0 = (blockIdx.x * 4 + w) * 16;
  const int m = lane & 15, b = lane >> 4;
  const int arow = row0 + m;
  const bool rok = arow < N;
  const fp16x8* WT = (const fp16x8*)kWt;

  fp16x8 zfr;
  #pragma unroll
  for (int i = 0; i < 8; ++i) zfr[i] = (_Float16)0.f;
  fp16x8 afr[4];
  {
    const size_t base = (size_t)arow * 128;
    #pragma unroll
    for (int ks = 0; ks < 4; ++ks) {
      if (rok) afr[ks] = packrow8h<0, IN16>(o, nullptr, 0.f, 0.f, base + ks * 32 + b * 8);
      else     afr[ks] = zfr;
    }
  }

  float sum = 0.f;
  #pragma unroll
  for (int t = 0; t < 8; ++t) {
    f32x4 acc = {0.f, 0.f, 0.f, 0.f};
    const int col = t * 16 + m;
    #pragma unroll
    for (int ks = 0; ks < 4; ++ks)
      acc = __builtin_amdgcn_mfma_f32_16x16x32_f16(afr[ks], WT[(t * 4 + ks) * 64 + lane], acc, 0, 0, 0);
    const float qc = q[col], kbc = kb[col];
    #pragma unroll
    for (int r = 0; r < 4; ++r) {
      int row = row0 + b * 4 + r;
      if (row < N) sum += qc * tanh_fast(acc[r] + kbc);
    }
  }
  #pragma unroll
  for (int off = 32; off > 0; off >>= 1) sum += __shfl_down(sum, off);
  if (lane == 0) partw[w] = sum;
  __syncthreads();
  if (tid == 0)
    atomicAdd(&slots[blockIdx.y],
              (partw[0] + partw[1] + partw[2] + partw[3]) * (1.f / (float)N));
}

__global__ void softmax2_kernel(float* sb)   // sb[0],sb[1] -> weights sb[2],sb[3]
{
  float s0 = sb[0], s1 = sb[1];
  float mx = fmaxf(s0, s1);
  float e0 = expf(s0 - mx), e1 = expf(s1 - mx);
  float inv = 1.f / (e0 + e1);
  sb[2] = e0 * inv;
  sb[3] = e1 * inv;
}

// ---- merged final projection via MFMA fp16 (fragment-ordered pWt) -------
template<int IN16>
__global__ __launch_bounds__(256)
void proj2_mfma(const void* __restrict__ fa, const void* __restrict__ fb,
                const float* __restrict__ wv, const void* __restrict__ fd,
                const unsigned short* __restrict__ pWt, const float* __restrict__ pb,
                float* __restrict__ outc, float* __restrict__ outd, int N)
{
  const bool isC = (blockIdx.y == 0);
  const int tid = threadIdx.x;
  const int w = tid >> 6, lane = tid & 63;
  const int row0 = (blockIdx.x * 4 + w) * 16;
  const int m = lane & 15, b = lane >> 4;
  const int arow = row0 + m;
  const bool rok = arow < N;
  float* out = isC ? outc : outd;
  const fp16x8* WT = (const fp16x8*)pWt;

  fp16x8 zfr;
  #pragma unroll
  for (int i = 0; i < 8; ++i) zfr[i] = (_Float16)0.f;
  fp16x8 afr[4];
  {
    const size_t base = (size_t)arow * 128;
    if (isC) {
      const float w2 = wv[2], w3 = wv[3];
      #pragma unroll
      for (int ks = 0; ks < 4; ++ks) {
        if (rok) afr[ks] = packrow8h<2, IN16>(fa, fb, w2, w3, base + ks * 32 + b * 8);
        else     afr[ks] = zfr;
      }
    } else {
      #pragma unroll
      for (int ks = 0; ks < 4; ++ks) {
        if (rok) afr[ks] = packrow8h<1, IN16>(fd, nullptr, 0.f, 0.f, base + ks * 32 + b * 8);
        else     afr[ks] = zfr;
      }
    }
  }

  f32x4 accs[4];
  float pbc[4];
  #pragma unroll
  for (int t = 0; t < 4; ++t) {
    f32x4 acc = {0.f, 0.f, 0.f, 0.f};
    const int col = t * 16 + m;
    #pragma unroll
    for (int ks = 0; ks < 4; ++ks)
      acc = __builtin_amdgcn_mfma_f32_16x16x32_f16(afr[ks], WT[(t * 4 + ks) * 64 + lane], acc, 0, 0, 0);
    accs[t] = acc;
    pbc[t] = pb[col];
  }

  #pragma unroll
  for (int r = 0; r < 4; ++r) {
    const int row = row0 + b * 4 + r;
    float v[4];
    #pragma unroll
    for (int t = 0; t < 4; ++t) v[t] = accs[t][r] + pbc[t];
    if (isC) {
      float ss = v[0]*v[0] + v[1]*v[1] + v[2]*v[2] + v[3]*v[3];
      ss += __shfl_xor(ss, 1);
      ss += __shfl_xor(ss, 2);
      ss += __shfl_xor(ss, 4);
      ss += __shfl_xor(ss, 8);
      float inv = 1.f / fmaxf(sqrtf(ss), 1e-12f);
      #pragma unroll
      for (int t = 0; t < 4; ++t) v[t] *= inv;
    }
    if (row < N) {
      #pragma unroll
      for (int t = 0; t < 4; ++t)
        out[(size_t)row * OUTn + t * 16 + m] = v[t];
    }
  }
}

// ---- fallback edge-op dispatcher ----------------------------------------
static void run_edge_fb(hipStream_t stream, const int* ei,
                        const float* sdot, const float* ddot, const float* hsrc,
                        float* outb, int Ndst,
                        unsigned* mbuf, float* sden, float* ebuf)
{
  hipMemsetAsync(mbuf, 0, (size_t)Ndst * 4 * sizeof(unsigned), stream);
  edge_logit_max<<<(En + 255) / 256, 256, 0, stream>>>(ei, sdot, ddot, mbuf);
  hipMemsetAsync(sden, 0, (size_t)Ndst * 4 * sizeof(float), stream);
  edge_exp_sum<<<(En + 255) / 256, 256, 0, stream>>>(ei, sdot, ddot, mbuf, sden, ebuf);
  hipMemsetAsync(outb, 0, (size_t)Ndst * HIDn * sizeof(float), stream);
  edge_scatter<<<((size_t)En * 64 + 255) / 256, 256, 0, stream>>>(ei, hsrc, ebuf, sden, outb);
  relu_k<<<((size_t)Ndst * HIDn + 255) / 256, 256, 0, stream>>>(outb, Ndst * HIDn);
}

extern "C" void kernel_launch(void* const* d_in, const int* in_sizes, int n_in,
                              void* d_out, int out_size, void* d_ws, size_t ws_size,
                              hipStream_t stream)
{
  const float* xc    = (const float*)d_in[0];
  const float* xd    = (const float*)d_in[1];
  const int*   ei_cc = (const int*)d_in[2];
  const int*   ei_dc = (const int*)d_in[3];
  const int*   ei_cd = (const int*)d_in[4];
  const float* W1c = (const float*)d_in[5];  const float* b1c = (const float*)d_in[6];
  const float* W1d = (const float*)d_in[7];  const float* b1d = (const float*)d_in[8];
  const float* a1s_cc = (const float*)d_in[9];  const float* a1d_cc = (const float*)d_in[10];
  const float* a1s_dc = (const float*)d_in[11]; const float* a1d_dc = (const float*)d_in[12];
  const float* a1s_cd = (const float*)d_in[13]; const float* a1d_cd = (const float*)d_in[14];
  const float* k1W = (const float*)d_in[15]; const float* k1b = (const float*)d_in[16];
  const float* q1  = (const float*)d_in[17];
  const float* W2c = (const float*)d_in[18]; const float* b2c = (const float*)d_in[19];
  const float* W2d = (const float*)d_in[20]; const float* b2d = (const float*)d_in[21];
  const float* a2s_cc = (const float*)d_in[22]; const float* a2d_cc = (const float*)d_in[23];
  const float* a2s_dc = (const float*)d_in[24]; const float* a2d_dc = (const float*)d_in[25];
  const float* a2s_cd = (const float*)d_in[26]; const float* a2d_cd = (const float*)d_in[27];
  const float* k2W = (const float*)d_in[28]; const float* k2b = (const float*)d_in[29];
  const float* q2  = (const float*)d_in[30];
  const float* pW  = (const float*)d_in[31]; const float* pb  = (const float*)d_in[32];

  // ---------------- workspace layout ----------------
  float* ws = (float*)d_ws;
  const size_t NB = (size_t)NCn * HIDn;
  float* B0 = ws;            // node buffers (fp16 in CSR mode, fp32 fallback)
  float* B1 = ws + NB;
  float* B2 = ws + 2 * NB;
  float* B3 = ws + 3 * NB;
  float* B4 = ws + 4 * NB;
  float* sml = ws + 5 * NB;
  float* scc = sml;
  float* dcc = sml + 200000;
  float* ddc = sml + 400000;
  float* scd = sml + 600000;
  float* sdc = sml + 800000;
  float* dcd = sml + 1000000;
  float* scoreB = sml + 1200000;
  float* R0 = sml + 1200016;
  int*  R0i = (int*)R0;
  int*  offsBase  = R0i;                   // 150,004 ints (global offs)
  int*  elistBase = R0i + 150004;          // 1,200,000 ints (combined)
  int*  degBase   = R0i + 1350004;         // 150,000
  int*  cursorBase= R0i + 1500004;         // 150,000 (adjacent -> single memset)
  int*  inclBase  = R0i + 1650004;         // 150,000
  int*  bsumBase  = R0i + 1800004;         // 1,024
  unsigned short* kW1t = (unsigned short*)(R0i + 1801028);
  unsigned short* kW2t = (unsigned short*)(R0i + 1809220);
  unsigned short* pWt  = (unsigned short*)(R0i + 1817412);
  unsigned short* W1cH = (unsigned short*)(R0i + 1821508);
  unsigned short* W1cL = (unsigned short*)(R0i + 1837892);
  unsigned short* W1dH = (unsigned short*)(R0i + 1854276);
  unsigned short* W1dL = (unsigned short*)(R0i + 1870660);
  unsigned short* W2cH = (unsigned short*)(R0i + 1887044);
  unsigned short* W2cL = (unsigned short*)(R0i + 1895236);
  unsigned short* W2dH = (unsigned short*)(R0i + 1903428);
  unsigned short* W2dL = (unsigned short*)(R0i + 1911620);  // end 1,919,812 ints
  // fallback temps overlay (over CSR region)
  unsigned* mbuf = (unsigned*)R0;
  float*    sden = R0 + 200000;
  float*    ebuf = R0 + 400000;

  const size_t REQ_FLOATS = 5 * NB + 1200016 + 1919812;     // 35,119,828 fl = 140.5 MB
  const bool useCsr = ws_size >= REQ_FLOATS * sizeof(float);

  if (useCsr) {
    hipMemsetAsync(degBase, 0, 300000 * sizeof(int), stream);   // deg + cursor
    hist3<<<(3 * En + 255) / 256, 256, 0, stream>>>(ei_cc, ei_dc, ei_cd, degBase);
    scan_pass1<<<SCAN_NB, SCAN_BLK, 0, stream>>>(degBase, inclBase, bsumBase);
    scan_pass2<<<1, SCAN_BLK, 0, stream>>>(bsumBase, SCAN_NB);
    scan_pass3<<<SCAN_NB, SCAN_BLK, 0, stream>>>(inclBase, bsumBase, offsBase);
    fill3<<<(3 * En + 255) / 256, 256, 0, stream>>>(ei_cc, ei_dc, ei_cd,
                                                    offsBase, cursorBase, elistBase);
  }
  wprep<<<(139264 + 255) / 256, 256, 0, stream>>>(k1W, k2W, pW, W1c, W1d, W2c, W2d,
                                                  kW1t, kW2t, pWt,
                                                  W1cH, W1cL, W1dH, W1dL,
                                                  W2cH, W2cL, W2dH, W2dL);

  hipMemsetAsync(scoreB, 0, 8 * sizeof(float), stream);

  const int NT64 = (NCn + 63) / 64;
  const int* offs0 = offsBase;
  const int* offs1 = offsBase + 50000;
  const int* offs2 = offsBase + 100000;

  auto edge_layer = [&](void* hc, void* hd, void* oCC, void* oDC, void* oCD) {
    if (useCsr) {
      EdgeOp o0{offs0, elistBase, scc, dcc, (const __half*)hc, (__half*)oCC};
      EdgeOp o1{offs1, elistBase, sdc, ddc, (const __half*)hd, (__half*)oDC};
      EdgeOp o2{offs2, elistBase, scd, dcd, (const __half*)hc, (__half*)oCD};
      csr_att3<<<dim3((NCn + 3) / 4, 3), 256, 0, stream>>>(o0, o1, o2, NCn);
    } else {
      run_edge_fb(stream, ei_cc, scc, dcc, (const float*)hc, (float*)oCC, NCn, mbuf, sden, ebuf);
      run_edge_fb(stream, ei_dc, sdc, ddc, (const float*)hd, (float*)oDC, NCn, mbuf, sden, ebuf);
      run_edge_fb(stream, ei_cd, scd, dcd, (const float*)hc, (float*)oCD, NDn, mbuf, sden, ebuf);
    }
  };

  if (useCsr) {
    // ---------------- layer 1 ----------------
    gemm2_mfma<256, 0, 0, 0, 1><<<dim3(NT64, 2), 256, 0, stream>>>(
        xc, nullptr, nullptr, W1cH, W1cL, b1c, B0,
        xd, W1dH, W1dL, b1d, B1, NCn,
        a1s_cc, a1d_cc, a1d_dc, a1s_cd, a1s_dc, a1d_cd,
        scc, dcc, ddc, scd, sdc, dcd);
    edge_layer(B0, B1, B2, B3, B4);
    score_mfma<1><<<dim3(NT64, 2), 256, 0, stream>>>(B2, B3, kW1t, k1b, q1, NCn, scoreB);
    softmax2_kernel<<<1, 1, 0, stream>>>(scoreB);

    // ---------------- layer 2 ----------------
    gemm2_mfma<128, 2, 1, 1, 1><<<dim3(NT64, 2), 256, 0, stream>>>(
        B2, B3, scoreB, W2cH, W2cL, b2c, B0,
        B4, W2dH, W2dL, b2d, B1, NCn,
        a2s_cc, a2d_cc, a2d_dc, a2s_cd, a2s_dc, a2d_cd,
        scc, dcc, ddc, scd, sdc, dcd);
    edge_layer(B0, B1, B2, B3, B4);
    score_mfma<1><<<dim3(NT64, 2), 256, 0, stream>>>(B2, B3, kW2t, k2b, q2, NCn, scoreB + 4);
    softmax2_kernel<<<1, 1, 0, stream>>>(scoreB + 4);

    // ---------------- projection (merged) ----------------
    proj2_mfma<1><<<dim3(NT64, 2), 256, 0, stream>>>(B2, B3, scoreB + 4, B4, pWt, pb,
                                                     (float*)d_out,
                                                     (float*)d_out + (size_t)NCn * OUTn, NCn);
  } else {
    // ---------------- fp32 fallback ----------------
    gemm2_mfma<256, 0, 0, 0, 0><<<dim3(NT64, 2), 256, 0, stream>>>(
        xc, nullptr, nullptr, W1cH, W1cL, b1c, B0,
        xd, W1dH, W1dL, b1d, B1, NCn,
        a1s_cc, a1d_cc, a1d_dc, a1s_cd, a1s_dc, a1d_cd,
        scc, dcc, ddc, scd, sdc, dcd);
    edge_layer(B0, B1, B2, B3, B4);
    score_mfma<0><<<dim3(NT64, 2), 256, 0, stream>>>(B2, B3, kW1t, k1b, q1, NCn, scoreB);
    softmax2_kernel<<<1, 1, 0, stream>>>(scoreB);

    gemm2_mfma<128, 2, 1, 0, 0><<<dim3(NT64, 2), 256, 0, stream>>>(
        B2, B3, scoreB, W2cH, W2cL, b2c, B0,
        B4, W2dH, W2dL, b2d, B1, NCn,
        a2s_cc, a2d_cc, a2d_dc, a2s_cd, a2s_dc, a2d_cd,
        scc, dcc, ddc, scd, sdc, dcd);
    edge_layer(B0, B1, B2, B3, B4);
    score_mfma<0><<<dim3(NT64, 2), 256, 0, stream>>>(B2, B3, kW2t, k2b, q2, NCn, scoreB + 4);
    softmax2_kernel<<<1, 1, 0, stream>>>(scoreB + 4);

    proj2_mfma<0><<<dim3(NT64, 2), 256, 0, stream>>>(B2, B3, scoreB + 4, B4, pWt, pb,
                                                     (float*)d_out,
                                                     (float*)d_out + (size_t)NCn * OUTn, NCn);
  }
}